// Round 1
// 228.223 us; speedup vs baseline: 1.0641x; 1.0641x over previous
//
#include <hip/hip_runtime.h>
#include <stdint.h>

typedef __bf16 bf16x8 __attribute__((ext_vector_type(8)));
typedef float f32x4v __attribute__((ext_vector_type(4)));
typedef float f32x16v __attribute__((ext_vector_type(16)));
typedef unsigned u32x2 __attribute__((ext_vector_type(2)));

// round-to-nearest bf16 (2 ops)
__device__ __forceinline__ unsigned f2bf_rn(float f) {
    return (__float_as_uint(f) + 0x8000u) >> 16;
}
// pack two floats -> two bf16 in one dword: 2 adds + 1 v_perm
__device__ __forceinline__ unsigned pk2bf(float a, float b) {
    return __builtin_amdgcn_perm(__float_as_uint(b) + 0x8000u,
                                 __float_as_uint(a) + 0x8000u, 0x07060302u);
}
// pack two floats -> two bf16 via HW v_cvt_pk_bf16_f32 (RNE). Per learn_hip
// m240: scalar (__bf16) casts are the fast path on gfx950 hipcc — the compiler
// fuses the pair into one v_cvt_pk_bf16_f32. 1 op vs pk2bf's 3.
__device__ __forceinline__ unsigned pk2bf_rne(float a, float b) {
    union { __bf16 h[2]; unsigned u; } x;
    x.h[0] = (__bf16)a; x.h[1] = (__bf16)b;
    return x.u;
}
// raw v_exp_f32: logits bounded (|x| << 126) so the LLVM denorm-guard
// sequence (~5 VALU ops) around llvm.exp2.f32 is pure waste.
__device__ __forceinline__ float fexp2(float x) {
#if __has_builtin(__builtin_amdgcn_exp2f)
    return __builtin_amdgcn_exp2f(x);
#else
    float r; asm volatile("v_exp_f32 %0, %1" : "=v"(r) : "v"(x)); return r;
#endif
}
// raw v_rcp_f32 (~1 ulp): fine for softmax denominator; avoids the ~10-op
// exact-division sequence.
__device__ __forceinline__ float frcp(float x) {
#if __has_builtin(__builtin_amdgcn_rcpf)
    return __builtin_amdgcn_rcpf(x);
#else
    float r; asm volatile("v_rcp_f32 %0, %1" : "=v"(r) : "v"(x)); return r;
#endif
}

// swap a.hi32lanes <-> b.lo32lanes (gfx950 v_permlane32_swap_b32)
__device__ __forceinline__ void swap32(unsigned &a, unsigned &b) {
#if __has_builtin(__builtin_amdgcn_permlane32_swap)
    u32x2 r = __builtin_amdgcn_permlane32_swap(a, b, false, false);
    a = r[0]; b = r[1];
#else
    unsigned pa = (unsigned)__shfl_xor((int)a, 32);
    unsigned pb = (unsigned)__shfl_xor((int)b, 32);
    bool hi = (threadIdx.x & 32) != 0;
    unsigned na = hi ? pb : a;
    unsigned nb = hi ? b : pa;
    a = na; b = nb;
#endif
}

__device__ __forceinline__ bf16x8 mk8(unsigned a, unsigned b, unsigned c, unsigned e) {
    union { int4 i; bf16x8 v; } u;
    u.i = make_int4((int)a, (int)b, (int)c, (int)e);
    return u.v;
}

#define GLD_LDS16(gp, lp) __builtin_amdgcn_global_load_lds( \
    (const __attribute__((address_space(1))) unsigned int*)(gp), \
    (__attribute__((address_space(3))) unsigned int*)(lp), 16, 0, 0)

// ---------------- weight transposes (both matrices, one launch) ----------------
__global__ __launch_bounds__(256) void wt_kernel(const float* __restrict__ wqkv,
        const float* __restrict__ wout, unsigned short* __restrict__ WqT,
        unsigned short* __restrict__ WoT) {
    __shared__ float tile[32][33];
    int bx = blockIdx.x;
    const float* in; unsigned short* out; int Cc, c0;
    if (bx < 48) { in = wqkv; out = WqT; Cc = 1536; c0 = bx * 32; }
    else         { in = wout; out = WoT; Cc = 512;  c0 = (bx - 48) * 32; }
    int r0 = blockIdx.y * 32;
    int tx = threadIdx.x & 31, ty = threadIdx.x >> 5;
    #pragma unroll
    for (int i = 0; i < 4; i++) {
        int r = ty + i * 8;
        tile[r][tx] = in[(size_t)(r0 + r) * Cc + c0 + tx];
    }
    __syncthreads();
    #pragma unroll
    for (int i = 0; i < 4; i++) {
        int cr = ty + i * 8;
        out[(size_t)(c0 + cr) * 512 + r0 + tx] = (unsigned short)f2bf_rn(tile[tx][cr]);
    }
}

// ---------------- GroupNorm -> hnT bf16 [n][s][c] ----------------
__global__ __launch_bounds__(256) void gn_kernel(const float* __restrict__ x,
        const float* __restrict__ scale, const float* __restrict__ bias,
        unsigned short* __restrict__ hnT) {
    int blk = blockIdx.x;                  // n*32+g
    int tid = threadIdx.x;
    int g = blk & 31, n = blk >> 5;
    const float4* src4 = (const float4*)(x + (size_t)blk * 16384);

    float s = 0.f, s2 = 0.f;
    for (int i = tid; i < 4096; i += 256) {
        float4 v = src4[i];
        s  += v.x + v.y + v.z + v.w;
        s2 += v.x*v.x + v.y*v.y + v.z*v.z + v.w*v.w;
    }
    __shared__ float red[256], red2[256];
    red[tid] = s; red2[tid] = s2;
    __syncthreads();
    for (int off = 128; off > 0; off >>= 1) {
        if (tid < off) { red[tid] += red[tid+off]; red2[tid] += red2[tid+off]; }
        __syncthreads();
    }
    __shared__ float sc_s[16], bi_s[16];
    if (tid < 16) {
        float mean = red[0] * (1.f/16384.f);
        float var  = red2[0] * (1.f/16384.f) - mean*mean;
        float rstd = rsqrtf(var + 1e-6f);
        int c = g*16 + tid;
        float sc = scale[c] * rstd;
        sc_s[tid] = sc;
        bi_s[tid] = bias[c] - mean * sc;
    }
    __shared__ float tile[16][260];
    for (int ch = 0; ch < 4; ch++) {
        __syncthreads();
        #pragma unroll
        for (int kk = 0; kk < 4; kk++) {
            int fi = tid + kk*256;
            int row = fi >> 6, col4 = fi & 63;
            float4 v = src4[row*256 + ch*64 + col4];
            *(float4*)&tile[row][col4*4] = v;
        }
        __syncthreads();
        int sQ = ch*256 + tid;
        unsigned int pk[8];
        #pragma unroll
        for (int c2 = 0; c2 < 8; c2++) {
            float a = tile[c2*2][tid]   * sc_s[c2*2]   + bi_s[c2*2];
            float b = tile[c2*2+1][tid] * sc_s[c2*2+1] + bi_s[c2*2+1];
            pk[c2] = pk2bf(a, b);
        }
        unsigned short* op = hnT + ((size_t)(n*1024 + sQ))*512 + g*16;
        *(uint4*)op       = make_uint4(pk[0], pk[1], pk[2], pk[3]);
        *((uint4*)op + 1) = make_uint4(pk[4], pk[5], pk[6], pk[7]);
    }
}

// ---------------- QKV GEMM: D[m][s] = sum_c WqT[m][c]*hnT[s][c] ----------------
__global__ __launch_bounds__(256) void qkv_kernel(
        const unsigned short* __restrict__ WqT, const unsigned short* __restrict__ hnT,
        const float* __restrict__ bqkv,
        unsigned short* __restrict__ qb, unsigned short* __restrict__ kbuf,
        unsigned short* __restrict__ vb) {
    int s0 = blockIdx.x * 128, m0 = blockIdx.y * 128, n = blockIdx.z;
    __shared__ unsigned short At[4096];    // 128 rows x 32 c, swizzled 16B chunks
    __shared__ unsigned short Bt[4096];
    int tid = threadIdx.x;
    int lane = tid & 63, w = tid >> 6;
    int quad = lane >> 4, tx = lane & 15;
    int moff = (w & 1) * 64, soff = (w >> 1) * 64;

    const unsigned short* Arow = WqT + (size_t)m0 * 512;
    const unsigned short* Brow = hnT + ((size_t)n * 1024 + s0) * 512;

    f32x4v acc[4][4];
    #pragma unroll
    for (int i = 0; i < 4; i++)
        #pragma unroll
        for (int j = 0; j < 4; j++)
            #pragma unroll
            for (int e = 0; e < 4; e++) acc[i][j][e] = 0.f;

    int f1 = tid, f2 = tid + 256;
    int m1 = f1 >> 2, kb1 = ((f1 & 3) - (f1 >> 3)) & 3;
    int m2 = f2 >> 2, kb2 = ((f2 & 3) - (f2 >> 3)) & 3;

    for (int k0 = 0; k0 < 512; k0 += 32) {
        __syncthreads();
        GLD_LDS16(Arow + (size_t)m1*512 + k0 + kb1*8, At + f1*8);
        GLD_LDS16(Arow + (size_t)m2*512 + k0 + kb2*8, At + f2*8);
        GLD_LDS16(Brow + (size_t)m1*512 + k0 + kb1*8, Bt + f1*8);
        GLD_LDS16(Brow + (size_t)m2*512 + k0 + kb2*8, Bt + f2*8);
        __syncthreads();
        bf16x8 af[4], bfr[4];
        #pragma unroll
        for (int mt = 0; mt < 4; mt++) {
            int m = moff + mt*16 + tx;
            int ch = m*4 + ((quad + (m >> 1)) & 3);
            af[mt] = *(const bf16x8*)(At + ch*8);
        }
        #pragma unroll
        for (int nt = 0; nt < 4; nt++) {
            int m = soff + nt*16 + tx;
            int ch = m*4 + ((quad + (m >> 1)) & 3);
            bfr[nt] = *(const bf16x8*)(Bt + ch*8);
        }
        #pragma unroll
        for (int mt = 0; mt < 4; mt++)
            #pragma unroll
            for (int nt = 0; nt < 4; nt++)
                acc[mt][nt] = __builtin_amdgcn_mfma_f32_16x16x32_bf16(
                    af[mt], bfr[nt], acc[mt][nt], 0, 0, 0);
    }

    // Epilogue: q scaled by 0.125*log2(e) (exp2-domain softmax downstream).
    const float QSCL = 0.18033688011112042f;
    #pragma unroll
    for (int mt = 0; mt < 4; mt++) {
        int m = m0 + moff + mt*16 + quad*4;
        int head = m / 192;
        int r = m - head*192;
        int which = r >> 6;
        int d0 = r & 63;
        float4 bia = *(const float4*)(bqkv + m);
        float scl = (which == 0) ? QSCL : 1.0f;
        #pragma unroll
        for (int nt = 0; nt < 4; nt++) {
            int sQ = s0 + soff + nt*16 + tx;
            f32x4v a = acc[mt][nt];
            float v0 = (a[0]+bia.x)*scl, v1 = (a[1]+bia.y)*scl;
            float v2 = (a[2]+bia.z)*scl, v3 = (a[3]+bia.w)*scl;
            if (which < 2) {
                unsigned short* base = (which == 0) ? qb : kbuf;
                unsigned lo = pk2bf(v0, v1), hi2 = pk2bf(v2, v3);
                *(uint2*)(base + (((size_t)(n*8 + head)*1024 + sQ) << 6) + d0) =
                    make_uint2(lo, hi2);
            } else {
                size_t vbase = ((size_t)(n*8 + head)*64 + d0)*1024 + sQ;
                vb[vbase]        = (unsigned short)f2bf_rn(v0);
                vb[vbase + 1024] = (unsigned short)f2bf_rn(v1);
                vb[vbase + 2048] = (unsigned short)f2bf_rn(v2);
                vb[vbase + 3072] = (unsigned short)f2bf_rn(v3);
            }
        }
    }
}

// ---------------- flash attention: in-register P transpose, pipelined staging ----
// Fixed-max exp2 softmax (logits are 0.18*(q.k), |logit| << 127 so no overflow).
// S^T = K*Q^T gives C-layout col=q, row=t; 4 permlane32_swap per 32-t block
// converts packed P dwords directly to the PV A-operand layout (no LDS trip).
// VALU diet vs prev round: raw v_exp_f32 (no denorm-guard sequence),
// v_cvt_pk_bf16_f32 packing, 4-way lsum accumulation, v_rcp_f32 epilogue.
__global__ __launch_bounds__(256) void attn_kernel(
        const unsigned short* __restrict__ qg, const unsigned short* __restrict__ kg,
        const unsigned short* __restrict__ vg, unsigned short* __restrict__ ao) {
    int bid = blockIdx.x;
    int nh = bid & 127, qbk = bid >> 7;     // 8 q-blocks of one head share an XCD
    int tid = threadIdx.x, w = tid >> 6, lane = tid & 63;
    int lq = lane & 31, hi = lane >> 5;
    const unsigned short* Q = qg + (size_t)nh * 65536;
    const unsigned short* K = kg + (size_t)nh * 65536;
    const unsigned short* V = vg + (size_t)nh * 65536;   // [d][t]

    __shared__ unsigned short Klds[2][64*72];            // [t][d], pad 8
    __shared__ unsigned short Vlds[2][64*72];            // [d][t], pad 8
    __shared__ float lsum_s[4][32];

    int q0 = qbk*128 + w*32;
    bf16x8 qf[4];
    #pragma unroll
    for (int ks = 0; ks < 4; ks++)
        qf[ks] = *(const bf16x8*)(Q + ((size_t)(q0 + lq))*64 + ks*16 + hi*8);

    // staging: each thread owns 32B of K-tile and V-tile
    int r = tid >> 2, part = (tid & 3) * 16;
    uint4 ka, kb2, va, vb2;
    ka  = *(const uint4*)(K + (size_t)r*64 + part);
    kb2 = *(const uint4*)(K + (size_t)r*64 + part + 8);
    va  = *(const uint4*)(V + (size_t)r*1024 + part);
    vb2 = *(const uint4*)(V + (size_t)r*1024 + part + 8);

    f32x16v O0, O1;
    #pragma unroll
    for (int i = 0; i < 16; i++) { O0[i] = 0.f; O1[i] = 0.f; }
    float l0 = 0.f, l1 = 0.f, l2 = 0.f, l3 = 0.f;

    for (int it = 0; it < 16; it++) {
        int buf = it & 1;
        {   // commit staged regs to LDS
            unsigned short* kd = Klds[buf] + r*72 + part;
            *(uint4*)kd = ka; *(uint4*)(kd+8) = kb2;
            unsigned short* vd = Vlds[buf] + r*72 + part;
            *(uint4*)vd = va; *(uint4*)(vd+8) = vb2;
        }
        __syncthreads();
        if (it < 15) {   // prefetch next tile (overlaps compute below)
            int t0 = (it + 1) * 64;
            ka  = *(const uint4*)(K + (size_t)(t0 + r)*64 + part);
            kb2 = *(const uint4*)(K + (size_t)(t0 + r)*64 + part + 8);
            va  = *(const uint4*)(V + (size_t)r*1024 + t0 + part);
            vb2 = *(const uint4*)(V + (size_t)r*1024 + t0 + part + 8);
        }
        const unsigned short* Kb = Klds[buf];
        const unsigned short* Vb = Vlds[buf];

        f32x16v S0, S1;
        #pragma unroll
        for (int i = 0; i < 16; i++) { S0[i] = 0.f; S1[i] = 0.f; }
        #pragma unroll
        for (int ks = 0; ks < 4; ks++) {
            bf16x8 a0 = *(const bf16x8*)(Kb + lq*72 + ks*16 + hi*8);
            bf16x8 a1 = *(const bf16x8*)(Kb + (32+lq)*72 + ks*16 + hi*8);
            S0 = __builtin_amdgcn_mfma_f32_32x32x16_bf16(a0, qf[ks], S0, 0, 0, 0);
            S1 = __builtin_amdgcn_mfma_f32_32x32x16_bf16(a1, qf[ks], S1, 0, 0, 0);
        }

        // p = exp2(S) via bare v_exp_f32; 4 independent lsum chains
        #pragma unroll
        for (int i = 0; i < 16; i++) {
            S0[i] = fexp2(S0[i]);
            S1[i] = fexp2(S1[i]);
        }
        #pragma unroll
        for (int i = 0; i < 4; i++) {
            l0 += S0[i];      l1 += S0[4+i];
            l2 += S0[8+i];    l3 += S0[12+i];
            l0 += S1[i];      l1 += S1[4+i];
            l2 += S1[8+i];    l3 += S1[12+i];
        }
        unsigned d[16];
        #pragma unroll
        for (int p2 = 0; p2 < 8; p2++) {
            d[p2]     = pk2bf_rne(S0[p2*2], S0[p2*2+1]);
            d[8 + p2] = pk2bf_rne(S1[p2*2], S1[p2*2+1]);
        }
        // in-register C->A transform: swap(d0,d2)->(A0,A2), swap(d1,d3)->(A1,A3)
        swap32(d[0],  d[2]);  swap32(d[1],  d[3]);
        swap32(d[4],  d[6]);  swap32(d[5],  d[7]);
        swap32(d[8],  d[10]); swap32(d[9],  d[11]);
        swap32(d[12], d[14]); swap32(d[13], d[15]);

        #pragma unroll
        for (int kc = 0; kc < 4; kc++) {
            bf16x8 pa = mk8(d[kc*4+0], d[kc*4+1], d[kc*4+2], d[kc*4+3]);
            bf16x8 v0 = *(const bf16x8*)(Vb + lq*72 + kc*16 + hi*8);
            bf16x8 v1 = *(const bf16x8*)(Vb + (32+lq)*72 + kc*16 + hi*8);
            O0 = __builtin_amdgcn_mfma_f32_32x32x16_bf16(pa, v0, O0, 0, 0, 0);
            O1 = __builtin_amdgcn_mfma_f32_32x32x16_bf16(pa, v1, O1, 0, 0, 0);
        }
    }

    float lsum = (l0 + l1) + (l2 + l3);
    lsum += __shfl_xor(lsum, 32);
    lsum_s[w][lq] = lsum;
    int n = nh >> 3, h = nh & 7;
    #pragma unroll
    for (int rq = 0; rq < 4; rq++) {
        float4 lv = *(const float4*)&lsum_s[w][rq*8 + hi*4];
        float invs[4] = {frcp(lv.x), frcp(lv.y), frcp(lv.z), frcp(lv.w)};
        #pragma unroll
        for (int i = 0; i < 4; i++) {
            int sQ = q0 + rq*8 + hi*4 + i;
            size_t rowb = ((size_t)(n*1024 + sQ))*512 + h*64;
            ao[rowb + lq]      = (unsigned short)f2bf_rn(O0[rq*4+i] * invs[i]);
            ao[rowb + 32 + lq] = (unsigned short)f2bf_rn(O1[rq*4+i] * invs[i]);
        }
    }
}

// ---------------- out GEMM: D[s][d] = sum_c aoT[s][c]*WoT[d][c]; +bias+x ----------------
__global__ __launch_bounds__(256) void out_kernel(
        const unsigned short* __restrict__ aoT, const unsigned short* __restrict__ WoT,
        const float* __restrict__ bout, const float* __restrict__ x,
        float* __restrict__ out) {
    int s0 = blockIdx.x * 128, d0b = blockIdx.y * 128, n = blockIdx.z;
    __shared__ unsigned short At[4096];
    __shared__ unsigned short Bt[4096];
    int tid = threadIdx.x;
    int lane = tid & 63, w = tid >> 6;
    int quad = lane >> 4, tx = lane & 15;
    int moff = (w & 1) * 64, noff = (w >> 1) * 64;

    const unsigned short* Arow = aoT + ((size_t)n * 1024 + s0) * 512;
    const unsigned short* Brow = WoT + (size_t)d0b * 512;

    f32x4v acc[4][4];
    #pragma unroll
    for (int i = 0; i < 4; i++)
        #pragma unroll
        for (int j = 0; j < 4; j++)
            #pragma unroll
            for (int e = 0; e < 4; e++) acc[i][j][e] = 0.f;

    int f1 = tid, f2 = tid + 256;
    int m1 = f1 >> 2, kb1 = ((f1 & 3) - (f1 >> 3)) & 3;
    int m2 = f2 >> 2, kb2 = ((f2 & 3) - (f2 >> 3)) & 3;

    for (int k0 = 0; k0 < 512; k0 += 32) {
        __syncthreads();
        GLD_LDS16(Arow + (size_t)m1*512 + k0 + kb1*8, At + f1*8);
        GLD_LDS16(Arow + (size_t)m2*512 + k0 + kb2*8, At + f2*8);
        GLD_LDS16(Brow + (size_t)m1*512 + k0 + kb1*8, Bt + f1*8);
        GLD_LDS16(Brow + (size_t)m2*512 + k0 + kb2*8, Bt + f2*8);
        __syncthreads();
        bf16x8 af[4], bfr[4];
        #pragma unroll
        for (int mt = 0; mt < 4; mt++) {
            int m = moff + mt*16 + tx;
            int ch = m*4 + ((quad + (m >> 1)) & 3);
            af[mt] = *(const bf16x8*)(At + ch*8);
        }
        #pragma unroll
        for (int nt = 0; nt < 4; nt++) {
            int m = noff + nt*16 + tx;
            int ch = m*4 + ((quad + (m >> 1)) & 3);
            bfr[nt] = *(const bf16x8*)(Bt + ch*8);
        }
        #pragma unroll
        for (int mt = 0; mt < 4; mt++)
            #pragma unroll
            for (int nt = 0; nt < 4; nt++)
                acc[mt][nt] = __builtin_amdgcn_mfma_f32_16x16x32_bf16(
                    af[mt], bfr[nt], acc[mt][nt], 0, 0, 0);
    }

    #pragma unroll
    for (int mt = 0; mt < 4; mt++) {
        int sQ = s0 + moff + mt*16 + quad*4;
        #pragma unroll
        for (int nt = 0; nt < 4; nt++) {
            int d = d0b + noff + nt*16 + tx;
            float bo = bout[d];
            size_t base = ((size_t)n*512 + d)*1024 + sQ;
            float4 xv = *(const float4*)(x + base);
            f32x4v a = acc[mt][nt];
            float4 o = make_float4(a[0]+bo+xv.x, a[1]+bo+xv.y, a[2]+bo+xv.z, a[3]+bo+xv.w);
            *(float4*)(out + base) = o;
        }
    }
}

extern "C" void kernel_launch(void* const* d_in, const int* in_sizes, int n_in,
                              void* d_out, int out_size, void* d_ws, size_t ws_size,
                              hipStream_t stream) {
    const float* x    = (const float*)d_in[0];
    const float* gns  = (const float*)d_in[1];
    const float* gnb  = (const float*)d_in[2];
    const float* wqkv = (const float*)d_in[3];
    const float* bqkv = (const float*)d_in[4];
    const float* wout = (const float*)d_in[5];
    const float* bout = (const float*)d_in[6];
    float* out = (float*)d_out;

    char* p = (char*)d_ws;
    size_t off = 0;
    auto carve = [&](size_t bytes) {
        char* r = p + off;
        off = (off + bytes + 255) & ~(size_t)255;
        return r;
    };
    unsigned short* hnT = (unsigned short*)carve((size_t)16*1024*512*2);
    unsigned short* qb2 = (unsigned short*)carve((size_t)128*1024*64*2);
    unsigned short* kb2 = (unsigned short*)carve((size_t)128*1024*64*2);
    unsigned short* vb2 = (unsigned short*)carve((size_t)128*64*1024*2);
    unsigned short* aoT = (unsigned short*)carve((size_t)16*1024*512*2);
    unsigned short* WqT = (unsigned short*)carve((size_t)1536*512*2);
    unsigned short* WoT = (unsigned short*)carve((size_t)512*512*2);

    wt_kernel<<<dim3(64, 16), 256, 0, stream>>>(wqkv, wout, WqT, WoT);
    gn_kernel<<<dim3(512), 256, 0, stream>>>(x, gns, gnb, hnT);
    qkv_kernel<<<dim3(8, 12, 16), 256, 0, stream>>>(WqT, hnT, bqkv, qb2, kb2, vb2);
    attn_kernel<<<dim3(1024), 256, 0, stream>>>(qb2, kb2, vb2, aoT);
    out_kernel<<<dim3(8, 4, 16), 256, 0, stream>>>(aoT, WoT, bout, x, out);
}

// Round 2
// 225.367 us; speedup vs baseline: 1.0776x; 1.0127x over previous
//
#include <hip/hip_runtime.h>
#include <stdint.h>

typedef __bf16 bf16x8 __attribute__((ext_vector_type(8)));
typedef float f32x4v __attribute__((ext_vector_type(4)));
typedef float f32x16v __attribute__((ext_vector_type(16)));
typedef unsigned u32x2 __attribute__((ext_vector_type(2)));

// round-to-nearest bf16 (2 ops)
__device__ __forceinline__ unsigned f2bf_rn(float f) {
    return (__float_as_uint(f) + 0x8000u) >> 16;
}
// pack two floats -> two bf16 in one dword: 2 adds + 1 v_perm
__device__ __forceinline__ unsigned pk2bf(float a, float b) {
    return __builtin_amdgcn_perm(__float_as_uint(b) + 0x8000u,
                                 __float_as_uint(a) + 0x8000u, 0x07060302u);
}
// pack two floats -> two bf16 via HW v_cvt_pk_bf16_f32 (RNE).
__device__ __forceinline__ unsigned pk2bf_rne(float a, float b) {
    union { __bf16 h[2]; unsigned u; } x;
    x.h[0] = (__bf16)a; x.h[1] = (__bf16)b;
    return x.u;
}
// raw v_exp_f32: logits bounded (|x| << 126) so the LLVM denorm-guard
// sequence (~5 VALU ops) around llvm.exp2.f32 is pure waste.
__device__ __forceinline__ float fexp2(float x) {
#if __has_builtin(__builtin_amdgcn_exp2f)
    return __builtin_amdgcn_exp2f(x);
#else
    float r; asm volatile("v_exp_f32 %0, %1" : "=v"(r) : "v"(x)); return r;
#endif
}
// raw v_rcp_f32 (~1 ulp): fine for softmax denominator.
__device__ __forceinline__ float frcp(float x) {
#if __has_builtin(__builtin_amdgcn_rcpf)
    return __builtin_amdgcn_rcpf(x);
#else
    float r; asm volatile("v_rcp_f32 %0, %1" : "=v"(r) : "v"(x)); return r;
#endif
}

// swap a.hi32lanes <-> b.lo32lanes (gfx950 v_permlane32_swap_b32)
__device__ __forceinline__ void swap32(unsigned &a, unsigned &b) {
#if __has_builtin(__builtin_amdgcn_permlane32_swap)
    u32x2 r = __builtin_amdgcn_permlane32_swap(a, b, false, false);
    a = r[0]; b = r[1];
#else
    unsigned pa = (unsigned)__shfl_xor((int)a, 32);
    unsigned pb = (unsigned)__shfl_xor((int)b, 32);
    bool hi = (threadIdx.x & 32) != 0;
    unsigned na = hi ? pb : a;
    unsigned nb = hi ? b : pa;
    a = na; b = nb;
#endif
}

__device__ __forceinline__ bf16x8 mk8(unsigned a, unsigned b, unsigned c, unsigned e) {
    union { int4 i; bf16x8 v; } u;
    u.i = make_int4((int)a, (int)b, (int)c, (int)e);
    return u.v;
}

#define GLD_LDS16(gp, lp) __builtin_amdgcn_global_load_lds( \
    (const __attribute__((address_space(1))) unsigned int*)(gp), \
    (__attribute__((address_space(3))) unsigned int*)(lp), 16, 0, 0)

// ---------------- weight transposes (both matrices, one launch) ----------------
__global__ __launch_bounds__(256) void wt_kernel(const float* __restrict__ wqkv,
        const float* __restrict__ wout, unsigned short* __restrict__ WqT,
        unsigned short* __restrict__ WoT) {
    __shared__ float tile[32][33];
    int bx = blockIdx.x;
    const float* in; unsigned short* out; int Cc, c0;
    if (bx < 48) { in = wqkv; out = WqT; Cc = 1536; c0 = bx * 32; }
    else         { in = wout; out = WoT; Cc = 512;  c0 = (bx - 48) * 32; }
    int r0 = blockIdx.y * 32;
    int tx = threadIdx.x & 31, ty = threadIdx.x >> 5;
    #pragma unroll
    for (int i = 0; i < 4; i++) {
        int r = ty + i * 8;
        tile[r][tx] = in[(size_t)(r0 + r) * Cc + c0 + tx];
    }
    __syncthreads();
    #pragma unroll
    for (int i = 0; i < 4; i++) {
        int cr = ty + i * 8;
        out[(size_t)(c0 + cr) * 512 + r0 + tx] = (unsigned short)f2bf_rn(tile[tx][cr]);
    }
}

// ---------------- GroupNorm -> hnT bf16 [n][s][c] ----------------
__global__ __launch_bounds__(256) void gn_kernel(const float* __restrict__ x,
        const float* __restrict__ scale, const float* __restrict__ bias,
        unsigned short* __restrict__ hnT) {
    int blk = blockIdx.x;                  // n*32+g
    int tid = threadIdx.x;
    int g = blk & 31, n = blk >> 5;
    const float4* src4 = (const float4*)(x + (size_t)blk * 16384);

    float s = 0.f, s2 = 0.f;
    for (int i = tid; i < 4096; i += 256) {
        float4 v = src4[i];
        s  += v.x + v.y + v.z + v.w;
        s2 += v.x*v.x + v.y*v.y + v.z*v.z + v.w*v.w;
    }
    __shared__ float red[256], red2[256];
    red[tid] = s; red2[tid] = s2;
    __syncthreads();
    for (int off = 128; off > 0; off >>= 1) {
        if (tid < off) { red[tid] += red[tid+off]; red2[tid] += red2[tid+off]; }
        __syncthreads();
    }
    __shared__ float sc_s[16], bi_s[16];
    if (tid < 16) {
        float mean = red[0] * (1.f/16384.f);
        float var  = red2[0] * (1.f/16384.f) - mean*mean;
        float rstd = rsqrtf(var + 1e-6f);
        int c = g*16 + tid;
        float sc = scale[c] * rstd;
        sc_s[tid] = sc;
        bi_s[tid] = bias[c] - mean * sc;
    }
    __shared__ float tile[16][260];
    for (int ch = 0; ch < 4; ch++) {
        __syncthreads();
        #pragma unroll
        for (int kk = 0; kk < 4; kk++) {
            int fi = tid + kk*256;
            int row = fi >> 6, col4 = fi & 63;
            float4 v = src4[row*256 + ch*64 + col4];
            *(float4*)&tile[row][col4*4] = v;
        }
        __syncthreads();
        int sQ = ch*256 + tid;
        unsigned int pk[8];
        #pragma unroll
        for (int c2 = 0; c2 < 8; c2++) {
            float a = tile[c2*2][tid]   * sc_s[c2*2]   + bi_s[c2*2];
            float b = tile[c2*2+1][tid] * sc_s[c2*2+1] + bi_s[c2*2+1];
            pk[c2] = pk2bf(a, b);
        }
        unsigned short* op = hnT + ((size_t)(n*1024 + sQ))*512 + g*16;
        *(uint4*)op       = make_uint4(pk[0], pk[1], pk[2], pk[3]);
        *((uint4*)op + 1) = make_uint4(pk[4], pk[5], pk[6], pk[7]);
    }
}

// ---------------- QKV GEMM: D[m][s] = sum_c WqT[m][c]*hnT[s][c] ----------------
__global__ __launch_bounds__(256) void qkv_kernel(
        const unsigned short* __restrict__ WqT, const unsigned short* __restrict__ hnT,
        const float* __restrict__ bqkv,
        unsigned short* __restrict__ qb, unsigned short* __restrict__ kbuf,
        unsigned short* __restrict__ vb) {
    int s0 = blockIdx.x * 128, m0 = blockIdx.y * 128, n = blockIdx.z;
    __shared__ unsigned short At[4096];    // 128 rows x 32 c, swizzled 16B chunks
    __shared__ unsigned short Bt[4096];
    int tid = threadIdx.x;
    int lane = tid & 63, w = tid >> 6;
    int quad = lane >> 4, tx = lane & 15;
    int moff = (w & 1) * 64, soff = (w >> 1) * 64;

    const unsigned short* Arow = WqT + (size_t)m0 * 512;
    const unsigned short* Brow = hnT + ((size_t)n * 1024 + s0) * 512;

    f32x4v acc[4][4];
    #pragma unroll
    for (int i = 0; i < 4; i++)
        #pragma unroll
        for (int j = 0; j < 4; j++)
            #pragma unroll
            for (int e = 0; e < 4; e++) acc[i][j][e] = 0.f;

    int f1 = tid, f2 = tid + 256;
    int m1 = f1 >> 2, kb1 = ((f1 & 3) - (f1 >> 3)) & 3;
    int m2 = f2 >> 2, kb2 = ((f2 & 3) - (f2 >> 3)) & 3;

    for (int k0 = 0; k0 < 512; k0 += 32) {
        __syncthreads();
        GLD_LDS16(Arow + (size_t)m1*512 + k0 + kb1*8, At + f1*8);
        GLD_LDS16(Arow + (size_t)m2*512 + k0 + kb2*8, At + f2*8);
        GLD_LDS16(Brow + (size_t)m1*512 + k0 + kb1*8, Bt + f1*8);
        GLD_LDS16(Brow + (size_t)m2*512 + k0 + kb2*8, Bt + f2*8);
        __syncthreads();
        bf16x8 af[4], bfr[4];
        #pragma unroll
        for (int mt = 0; mt < 4; mt++) {
            int m = moff + mt*16 + tx;
            int ch = m*4 + ((quad + (m >> 1)) & 3);
            af[mt] = *(const bf16x8*)(At + ch*8);
        }
        #pragma unroll
        for (int nt = 0; nt < 4; nt++) {
            int m = soff + nt*16 + tx;
            int ch = m*4 + ((quad + (m >> 1)) & 3);
            bfr[nt] = *(const bf16x8*)(Bt + ch*8);
        }
        #pragma unroll
        for (int mt = 0; mt < 4; mt++)
            #pragma unroll
            for (int nt = 0; nt < 4; nt++)
                acc[mt][nt] = __builtin_amdgcn_mfma_f32_16x16x32_bf16(
                    af[mt], bfr[nt], acc[mt][nt], 0, 0, 0);
    }

    // Epilogue: q scaled by 0.125*log2(e) (exp2-domain softmax downstream).
    const float QSCL = 0.18033688011112042f;
    #pragma unroll
    for (int mt = 0; mt < 4; mt++) {
        int m = m0 + moff + mt*16 + quad*4;
        int head = m / 192;
        int r = m - head*192;
        int which = r >> 6;
        int d0 = r & 63;
        float4 bia = *(const float4*)(bqkv + m);
        float scl = (which == 0) ? QSCL : 1.0f;
        #pragma unroll
        for (int nt = 0; nt < 4; nt++) {
            int sQ = s0 + soff + nt*16 + tx;
            f32x4v a = acc[mt][nt];
            float v0 = (a[0]+bia.x)*scl, v1 = (a[1]+bia.y)*scl;
            float v2 = (a[2]+bia.z)*scl, v3 = (a[3]+bia.w)*scl;
            if (which < 2) {
                unsigned short* base = (which == 0) ? qb : kbuf;
                unsigned lo = pk2bf(v0, v1), hi2 = pk2bf(v2, v3);
                *(uint2*)(base + (((size_t)(n*8 + head)*1024 + sQ) << 6) + d0) =
                    make_uint2(lo, hi2);
            } else {
                size_t vbase = ((size_t)(n*8 + head)*64 + d0)*1024 + sQ;
                vb[vbase]        = (unsigned short)f2bf_rn(v0);
                vb[vbase + 1024] = (unsigned short)f2bf_rn(v1);
                vb[vbase + 2048] = (unsigned short)f2bf_rn(v2);
                vb[vbase + 3072] = (unsigned short)f2bf_rn(v3);
            }
        }
    }
}

// ---------------- flash attention: in-register P transpose, pipelined staging ----
// Fixed-max exp2 softmax (logits are 0.18*(q.k), |logit| << 127 so no overflow).
// S^T = K*Q^T gives C-layout col=q, row=t; 4 permlane32_swap per 32-t block
// converts packed P dwords directly to the PV A-operand layout (no LDS trip).
// Round-2 VALU diet: softmax denominator computed on the MFMA pipe via an
// all-ones B operand (Osum = P @ ones), same C/D layout as O0/O1 -> the
// per-q denominator is lane-local in the epilogue (no shfl / LDS reduce).
__global__ __launch_bounds__(256) void attn_kernel(
        const unsigned short* __restrict__ qg, const unsigned short* __restrict__ kg,
        const unsigned short* __restrict__ vg, unsigned short* __restrict__ ao) {
    int bid = blockIdx.x;
    int nh = bid & 127, qbk = bid >> 7;     // 8 q-blocks of one head share an XCD
    int tid = threadIdx.x, w = tid >> 6, lane = tid & 63;
    int lq = lane & 31, hi = lane >> 5;
    const unsigned short* Q = qg + (size_t)nh * 65536;
    const unsigned short* K = kg + (size_t)nh * 65536;
    const unsigned short* V = vg + (size_t)nh * 65536;   // [d][t]

    __shared__ unsigned short Klds[2][64*72];            // [t][d], pad 8
    __shared__ unsigned short Vlds[2][64*72];            // [d][t], pad 8

    int q0 = qbk*128 + w*32;
    bf16x8 qf[4];
    #pragma unroll
    for (int ks = 0; ks < 4; ks++)
        qf[ks] = *(const bf16x8*)(Q + ((size_t)(q0 + lq))*64 + ks*16 + hi*8);

    // staging: each thread owns 32B of K-tile and V-tile
    int r = tid >> 2, part = (tid & 3) * 16;
    uint4 ka, kb2, va, vb2;
    ka  = *(const uint4*)(K + (size_t)r*64 + part);
    kb2 = *(const uint4*)(K + (size_t)r*64 + part + 8);
    va  = *(const uint4*)(V + (size_t)r*1024 + part);
    vb2 = *(const uint4*)(V + (size_t)r*1024 + part + 8);

    // all-ones bf16 B operand (layout-irrelevant: every element is 1.0)
    const bf16x8 ONES = mk8(0x3f803f80u, 0x3f803f80u, 0x3f803f80u, 0x3f803f80u);

    f32x16v O0, O1, Os;
    #pragma unroll
    for (int i = 0; i < 16; i++) { O0[i] = 0.f; O1[i] = 0.f; Os[i] = 0.f; }

    for (int it = 0; it < 16; it++) {
        int buf = it & 1;
        {   // commit staged regs to LDS
            unsigned short* kd = Klds[buf] + r*72 + part;
            *(uint4*)kd = ka; *(uint4*)(kd+8) = kb2;
            unsigned short* vd = Vlds[buf] + r*72 + part;
            *(uint4*)vd = va; *(uint4*)(vd+8) = vb2;
        }
        __syncthreads();
        if (it < 15) {   // prefetch next tile (overlaps compute below)
            int t0 = (it + 1) * 64;
            ka  = *(const uint4*)(K + (size_t)(t0 + r)*64 + part);
            kb2 = *(const uint4*)(K + (size_t)(t0 + r)*64 + part + 8);
            va  = *(const uint4*)(V + (size_t)r*1024 + t0 + part);
            vb2 = *(const uint4*)(V + (size_t)r*1024 + t0 + part + 8);
        }
        const unsigned short* Kb = Klds[buf];
        const unsigned short* Vb = Vlds[buf];

        f32x16v S0, S1;
        #pragma unroll
        for (int i = 0; i < 16; i++) { S0[i] = 0.f; S1[i] = 0.f; }
        #pragma unroll
        for (int ks = 0; ks < 4; ks++) {
            bf16x8 a0 = *(const bf16x8*)(Kb + lq*72 + ks*16 + hi*8);
            bf16x8 a1 = *(const bf16x8*)(Kb + (32+lq)*72 + ks*16 + hi*8);
            S0 = __builtin_amdgcn_mfma_f32_32x32x16_bf16(a0, qf[ks], S0, 0, 0, 0);
            S1 = __builtin_amdgcn_mfma_f32_32x32x16_bf16(a1, qf[ks], S1, 0, 0, 0);
        }

        // p = exp2(S) via bare v_exp_f32
        #pragma unroll
        for (int i = 0; i < 16; i++) {
            S0[i] = fexp2(S0[i]);
            S1[i] = fexp2(S1[i]);
        }
        unsigned d[16];
        #pragma unroll
        for (int p2 = 0; p2 < 8; p2++) {
            d[p2]     = pk2bf_rne(S0[p2*2], S0[p2*2+1]);
            d[8 + p2] = pk2bf_rne(S1[p2*2], S1[p2*2+1]);
        }
        // in-register C->A transform: swap(d0,d2)->(A0,A2), swap(d1,d3)->(A1,A3)
        swap32(d[0],  d[2]);  swap32(d[1],  d[3]);
        swap32(d[4],  d[6]);  swap32(d[5],  d[7]);
        swap32(d[8],  d[10]); swap32(d[9],  d[11]);
        swap32(d[12], d[14]); swap32(d[13], d[15]);

        #pragma unroll
        for (int kc = 0; kc < 4; kc++) {
            bf16x8 pa = mk8(d[kc*4+0], d[kc*4+1], d[kc*4+2], d[kc*4+3]);
            bf16x8 v0 = *(const bf16x8*)(Vb + lq*72 + kc*16 + hi*8);
            bf16x8 v1 = *(const bf16x8*)(Vb + (32+lq)*72 + kc*16 + hi*8);
            O0 = __builtin_amdgcn_mfma_f32_32x32x16_bf16(pa, v0, O0, 0, 0, 0);
            O1 = __builtin_amdgcn_mfma_f32_32x32x16_bf16(pa, v1, O1, 0, 0, 0);
            Os = __builtin_amdgcn_mfma_f32_32x32x16_bf16(pa, ONES, Os, 0, 0, 0);
        }
    }

    // Os[reg] = sum_t P[t][q(reg-row)] (all 32 columns identical) -> lane-local
    int n = nh >> 3, h = nh & 7;
    #pragma unroll
    for (int rq = 0; rq < 4; rq++) {
        #pragma unroll
        for (int i = 0; i < 4; i++) {
            int reg = rq*4 + i;
            int sQ = q0 + rq*8 + hi*4 + i;
            float inv = frcp(Os[reg]);
            size_t rowb = ((size_t)(n*1024 + sQ))*512 + h*64;
            ao[rowb + lq]      = (unsigned short)f2bf_rn(O0[reg] * inv);
            ao[rowb + 32 + lq] = (unsigned short)f2bf_rn(O1[reg] * inv);
        }
    }
}

// ---------------- out GEMM: D[s][d] = sum_c aoT[s][c]*WoT[d][c]; +bias+x ----------------
__global__ __launch_bounds__(256) void out_kernel(
        const unsigned short* __restrict__ aoT, const unsigned short* __restrict__ WoT,
        const float* __restrict__ bout, const float* __restrict__ x,
        float* __restrict__ out) {
    int s0 = blockIdx.x * 128, d0b = blockIdx.y * 128, n = blockIdx.z;
    __shared__ unsigned short At[4096];
    __shared__ unsigned short Bt[4096];
    int tid = threadIdx.x;
    int lane = tid & 63, w = tid >> 6;
    int quad = lane >> 4, tx = lane & 15;
    int moff = (w & 1) * 64, noff = (w >> 1) * 64;

    const unsigned short* Arow = aoT + ((size_t)n * 1024 + s0) * 512;
    const unsigned short* Brow = WoT + (size_t)d0b * 512;

    f32x4v acc[4][4];
    #pragma unroll
    for (int i = 0; i < 4; i++)
        #pragma unroll
        for (int j = 0; j < 4; j++)
            #pragma unroll
            for (int e = 0; e < 4; e++) acc[i][j][e] = 0.f;

    int f1 = tid, f2 = tid + 256;
    int m1 = f1 >> 2, kb1 = ((f1 & 3) - (f1 >> 3)) & 3;
    int m2 = f2 >> 2, kb2 = ((f2 & 3) - (f2 >> 3)) & 3;

    for (int k0 = 0; k0 < 512; k0 += 32) {
        __syncthreads();
        GLD_LDS16(Arow + (size_t)m1*512 + k0 + kb1*8, At + f1*8);
        GLD_LDS16(Arow + (size_t)m2*512 + k0 + kb2*8, At + f2*8);
        GLD_LDS16(Brow + (size_t)m1*512 + k0 + kb1*8, Bt + f1*8);
        GLD_LDS16(Brow + (size_t)m2*512 + k0 + kb2*8, Bt + f2*8);
        __syncthreads();
        bf16x8 af[4], bfr[4];
        #pragma unroll
        for (int mt = 0; mt < 4; mt++) {
            int m = moff + mt*16 + tx;
            int ch = m*4 + ((quad + (m >> 1)) & 3);
            af[mt] = *(const bf16x8*)(At + ch*8);
        }
        #pragma unroll
        for (int nt = 0; nt < 4; nt++) {
            int m = noff + nt*16 + tx;
            int ch = m*4 + ((quad + (m >> 1)) & 3);
            bfr[nt] = *(const bf16x8*)(Bt + ch*8);
        }
        #pragma unroll
        for (int mt = 0; mt < 4; mt++)
            #pragma unroll
            for (int nt = 0; nt < 4; nt++)
                acc[mt][nt] = __builtin_amdgcn_mfma_f32_16x16x32_bf16(
                    af[mt], bfr[nt], acc[mt][nt], 0, 0, 0);
    }

    #pragma unroll
    for (int mt = 0; mt < 4; mt++) {
        int sQ = s0 + moff + mt*16 + quad*4;
        #pragma unroll
        for (int nt = 0; nt < 4; nt++) {
            int d = d0b + noff + nt*16 + tx;
            float bo = bout[d];
            size_t base = ((size_t)n*512 + d)*1024 + sQ;
            float4 xv = *(const float4*)(x + base);
            f32x4v a = acc[mt][nt];
            float4 o = make_float4(a[0]+bo+xv.x, a[1]+bo+xv.y, a[2]+bo+xv.z, a[3]+bo+xv.w);
            *(float4*)(out + base) = o;
        }
    }
}

extern "C" void kernel_launch(void* const* d_in, const int* in_sizes, int n_in,
                              void* d_out, int out_size, void* d_ws, size_t ws_size,
                              hipStream_t stream) {
    const float* x    = (const float*)d_in[0];
    const float* gns  = (const float*)d_in[1];
    const float* gnb  = (const float*)d_in[2];
    const float* wqkv = (const float*)d_in[3];
    const float* bqkv = (const float*)d_in[4];
    const float* wout = (const float*)d_in[5];
    const float* bout = (const float*)d_in[6];
    float* out = (float*)d_out;

    char* p = (char*)d_ws;
    size_t off = 0;
    auto carve = [&](size_t bytes) {
        char* r = p + off;
        off = (off + bytes + 255) & ~(size_t)255;
        return r;
    };
    unsigned short* hnT = (unsigned short*)carve((size_t)16*1024*512*2);
    unsigned short* qb2 = (unsigned short*)carve((size_t)128*1024*64*2);
    unsigned short* kb2 = (unsigned short*)carve((size_t)128*1024*64*2);
    unsigned short* vb2 = (unsigned short*)carve((size_t)128*64*1024*2);
    unsigned short* aoT = (unsigned short*)carve((size_t)16*1024*512*2);
    unsigned short* WqT = (unsigned short*)carve((size_t)1536*512*2);
    unsigned short* WoT = (unsigned short*)carve((size_t)512*512*2);

    wt_kernel<<<dim3(64, 16), 256, 0, stream>>>(wqkv, wout, WqT, WoT);
    gn_kernel<<<dim3(512), 256, 0, stream>>>(x, gns, gnb, hnT);
    qkv_kernel<<<dim3(8, 12, 16), 256, 0, stream>>>(WqT, hnT, bqkv, qb2, kb2, vb2);
    attn_kernel<<<dim3(1024), 256, 0, stream>>>(qb2, kb2, vb2, aoT);
    out_kernel<<<dim3(8, 4, 16), 256, 0, stream>>>(aoT, WoT, bout, x, out);
}

// Round 3
// 208.678 us; speedup vs baseline: 1.1637x; 1.0800x over previous
//
#include <hip/hip_runtime.h>
#include <stdint.h>

typedef __bf16 bf16x8 __attribute__((ext_vector_type(8)));
typedef float f32x4v __attribute__((ext_vector_type(4)));
typedef float f32x16v __attribute__((ext_vector_type(16)));
typedef unsigned u32x2 __attribute__((ext_vector_type(2)));

// round-to-nearest bf16 (2 ops)
__device__ __forceinline__ unsigned f2bf_rn(float f) {
    return (__float_as_uint(f) + 0x8000u) >> 16;
}
// pack two floats -> two bf16 in one dword: 2 adds + 1 v_perm
__device__ __forceinline__ unsigned pk2bf(float a, float b) {
    return __builtin_amdgcn_perm(__float_as_uint(b) + 0x8000u,
                                 __float_as_uint(a) + 0x8000u, 0x07060302u);
}
// pack two floats -> two bf16 via HW v_cvt_pk_bf16_f32 (RNE).
__device__ __forceinline__ unsigned pk2bf_rne(float a, float b) {
    union { __bf16 h[2]; unsigned u; } x;
    x.h[0] = (__bf16)a; x.h[1] = (__bf16)b;
    return x.u;
}
// raw v_exp_f32: logits bounded (|x| << 126) so the LLVM denorm-guard
// sequence (~5 VALU ops) around llvm.exp2.f32 is pure waste.
__device__ __forceinline__ float fexp2(float x) {
#if __has_builtin(__builtin_amdgcn_exp2f)
    return __builtin_amdgcn_exp2f(x);
#else
    float r; asm volatile("v_exp_f32 %0, %1" : "=v"(r) : "v"(x)); return r;
#endif
}
// raw v_rcp_f32 (~1 ulp): fine for softmax denominator.
__device__ __forceinline__ float frcp(float x) {
#if __has_builtin(__builtin_amdgcn_rcpf)
    return __builtin_amdgcn_rcpf(x);
#else
    float r; asm volatile("v_rcp_f32 %0, %1" : "=v"(r) : "v"(x)); return r;
#endif
}

// swap a.hi32lanes <-> b.lo32lanes (gfx950 v_permlane32_swap_b32)
__device__ __forceinline__ void swap32(unsigned &a, unsigned &b) {
#if __has_builtin(__builtin_amdgcn_permlane32_swap)
    u32x2 r = __builtin_amdgcn_permlane32_swap(a, b, false, false);
    a = r[0]; b = r[1];
#else
    unsigned pa = (unsigned)__shfl_xor((int)a, 32);
    unsigned pb = (unsigned)__shfl_xor((int)b, 32);
    bool hi = (threadIdx.x & 32) != 0;
    unsigned na = hi ? pb : a;
    unsigned nb = hi ? b : pa;
    a = na; b = nb;
#endif
}

__device__ __forceinline__ bf16x8 mk8(unsigned a, unsigned b, unsigned c, unsigned e) {
    union { int4 i; bf16x8 v; } u;
    u.i = make_int4((int)a, (int)b, (int)c, (int)e);
    return u.v;
}

#define GLD_LDS16(gp, lp) __builtin_amdgcn_global_load_lds( \
    (const __attribute__((address_space(1))) unsigned int*)(gp), \
    (__attribute__((address_space(3))) unsigned int*)(lp), 16, 0, 0)

// ---------------- weight transposes (both matrices, one launch) ----------------
__global__ __launch_bounds__(256) void wt_kernel(const float* __restrict__ wqkv,
        const float* __restrict__ wout, unsigned short* __restrict__ WqT,
        unsigned short* __restrict__ WoT) {
    __shared__ float tile[32][33];
    int bx = blockIdx.x;
    const float* in; unsigned short* out; int Cc, c0;
    if (bx < 48) { in = wqkv; out = WqT; Cc = 1536; c0 = bx * 32; }
    else         { in = wout; out = WoT; Cc = 512;  c0 = (bx - 48) * 32; }
    int r0 = blockIdx.y * 32;
    int tx = threadIdx.x & 31, ty = threadIdx.x >> 5;
    #pragma unroll
    for (int i = 0; i < 4; i++) {
        int r = ty + i * 8;
        tile[r][tx] = in[(size_t)(r0 + r) * Cc + c0 + tx];
    }
    __syncthreads();
    #pragma unroll
    for (int i = 0; i < 4; i++) {
        int cr = ty + i * 8;
        out[(size_t)(c0 + cr) * 512 + r0 + tx] = (unsigned short)f2bf_rn(tile[tx][cr]);
    }
}

// ---------------- GroupNorm -> hnT bf16 [n][s][c] ----------------
// Single-pass: the 64 KB group-slab persists in LDS (grid = 2 blocks/CU, so
// 68 KB/block costs no occupancy); normalize pass reads LDS, not global.
__global__ __launch_bounds__(256) void gn_kernel(const float* __restrict__ x,
        const float* __restrict__ scale, const float* __restrict__ bias,
        unsigned short* __restrict__ hnT) {
    int blk = blockIdx.x;                  // n*32+g
    int tid = threadIdx.x;
    int g = blk & 31, n = blk >> 5;
    const float4* src4 = (const float4*)(x + (size_t)blk * 16384);

    __shared__ float xs[16][1028];         // 16 ch x 1024 px, +4 pad
    float s = 0.f, s2 = 0.f;
    #pragma unroll
    for (int k = 0; k < 16; k++) {
        int i = tid + k * 256;
        float4 v = src4[i];
        int c = i >> 8, p4 = (i & 255) * 4;
        *(float4*)&xs[c][p4] = v;
        s  += v.x + v.y + v.z + v.w;
        s2 += v.x*v.x + v.y*v.y + v.z*v.z + v.w*v.w;
    }
    __shared__ float red[256], red2[256];
    red[tid] = s; red2[tid] = s2;
    __syncthreads();
    for (int off = 128; off > 0; off >>= 1) {
        if (tid < off) { red[tid] += red[tid+off]; red2[tid] += red2[tid+off]; }
        __syncthreads();
    }
    __shared__ float sc_s[16], bi_s[16];
    if (tid < 16) {
        float mean = red[0] * (1.f/16384.f);
        float var  = red2[0] * (1.f/16384.f) - mean*mean;
        float rstd = rsqrtf(var + 1e-6f);
        int c = g*16 + tid;
        float sc = scale[c] * rstd;
        sc_s[tid] = sc;
        bi_s[tid] = bias[c] - mean * sc;
    }
    __syncthreads();
    #pragma unroll
    for (int ch = 0; ch < 4; ch++) {
        int sQ = ch*256 + tid;
        unsigned int pk[8];
        #pragma unroll
        for (int c2 = 0; c2 < 8; c2++) {
            float a = xs[c2*2][sQ]   * sc_s[c2*2]   + bi_s[c2*2];
            float b = xs[c2*2+1][sQ] * sc_s[c2*2+1] + bi_s[c2*2+1];
            pk[c2] = pk2bf(a, b);
        }
        unsigned short* op = hnT + ((size_t)(n*1024 + sQ))*512 + g*16;
        *(uint4*)op       = make_uint4(pk[0], pk[1], pk[2], pk[3]);
        *((uint4*)op + 1) = make_uint4(pk[4], pk[5], pk[6], pk[7]);
    }
}

// ---------------- QKV GEMM: D[m][s] = sum_c WqT[m][c]*hnT[s][c] ----------------
__global__ __launch_bounds__(256) void qkv_kernel(
        const unsigned short* __restrict__ WqT, const unsigned short* __restrict__ hnT,
        const float* __restrict__ bqkv,
        unsigned short* __restrict__ qb, unsigned short* __restrict__ kbuf,
        unsigned short* __restrict__ vb) {
    int s0 = blockIdx.x * 128, m0 = blockIdx.y * 128, n = blockIdx.z;
    __shared__ unsigned short At[4096];    // 128 rows x 32 c, swizzled 16B chunks
    __shared__ unsigned short Bt[4096];
    int tid = threadIdx.x;
    int lane = tid & 63, w = tid >> 6;
    int quad = lane >> 4, tx = lane & 15;
    int moff = (w & 1) * 64, soff = (w >> 1) * 64;

    const unsigned short* Arow = WqT + (size_t)m0 * 512;
    const unsigned short* Brow = hnT + ((size_t)n * 1024 + s0) * 512;

    f32x4v acc[4][4];
    #pragma unroll
    for (int i = 0; i < 4; i++)
        #pragma unroll
        for (int j = 0; j < 4; j++)
            #pragma unroll
            for (int e = 0; e < 4; e++) acc[i][j][e] = 0.f;

    int f1 = tid, f2 = tid + 256;
    int m1 = f1 >> 2, kb1 = ((f1 & 3) - (f1 >> 3)) & 3;
    int m2 = f2 >> 2, kb2 = ((f2 & 3) - (f2 >> 3)) & 3;

    for (int k0 = 0; k0 < 512; k0 += 32) {
        __syncthreads();
        GLD_LDS16(Arow + (size_t)m1*512 + k0 + kb1*8, At + f1*8);
        GLD_LDS16(Arow + (size_t)m2*512 + k0 + kb2*8, At + f2*8);
        GLD_LDS16(Brow + (size_t)m1*512 + k0 + kb1*8, Bt + f1*8);
        GLD_LDS16(Brow + (size_t)m2*512 + k0 + kb2*8, Bt + f2*8);
        __syncthreads();
        bf16x8 af[4], bfr[4];
        #pragma unroll
        for (int mt = 0; mt < 4; mt++) {
            int m = moff + mt*16 + tx;
            int ch = m*4 + ((quad + (m >> 1)) & 3);
            af[mt] = *(const bf16x8*)(At + ch*8);
        }
        #pragma unroll
        for (int nt = 0; nt < 4; nt++) {
            int m = soff + nt*16 + tx;
            int ch = m*4 + ((quad + (m >> 1)) & 3);
            bfr[nt] = *(const bf16x8*)(Bt + ch*8);
        }
        #pragma unroll
        for (int mt = 0; mt < 4; mt++)
            #pragma unroll
            for (int nt = 0; nt < 4; nt++)
                acc[mt][nt] = __builtin_amdgcn_mfma_f32_16x16x32_bf16(
                    af[mt], bfr[nt], acc[mt][nt], 0, 0, 0);
    }

    // Epilogue: q scaled by 0.125*log2(e) (exp2-domain softmax downstream).
    const float QSCL = 0.18033688011112042f;
    #pragma unroll
    for (int mt = 0; mt < 4; mt++) {
        int m = m0 + moff + mt*16 + quad*4;
        int head = m / 192;
        int r = m - head*192;
        int which = r >> 6;
        int d0 = r & 63;
        float4 bia = *(const float4*)(bqkv + m);
        float scl = (which == 0) ? QSCL : 1.0f;
        #pragma unroll
        for (int nt = 0; nt < 4; nt++) {
            int sQ = s0 + soff + nt*16 + tx;
            f32x4v a = acc[mt][nt];
            float v0 = (a[0]+bia.x)*scl, v1 = (a[1]+bia.y)*scl;
            float v2 = (a[2]+bia.z)*scl, v3 = (a[3]+bia.w)*scl;
            if (which < 2) {
                unsigned short* base = (which == 0) ? qb : kbuf;
                unsigned lo = pk2bf(v0, v1), hi2 = pk2bf(v2, v3);
                *(uint2*)(base + (((size_t)(n*8 + head)*1024 + sQ) << 6) + d0) =
                    make_uint2(lo, hi2);
            } else {
                size_t vbase = ((size_t)(n*8 + head)*64 + d0)*1024 + sQ;
                vb[vbase]        = (unsigned short)f2bf_rn(v0);
                vb[vbase + 1024] = (unsigned short)f2bf_rn(v1);
                vb[vbase + 2048] = (unsigned short)f2bf_rn(v2);
                vb[vbase + 3072] = (unsigned short)f2bf_rn(v3);
            }
        }
    }
}

// ---------------- flash attention: in-register P transpose, pipelined staging ----
// Fixed-max exp2 softmax (logits are 0.18*(q.k), |logit| << 127 so no overflow).
// S^T = K*Q^T gives C-layout col=q, row=t; 4 permlane32_swap per 32-t block
// converts packed P dwords directly to the PV A-operand layout (no LDS trip).
// Softmax denominator on the MFMA pipe (Osum = P @ ones, lane-local epilogue).
// Round-3: persistent ZED C-operand kills the 32 v_mov S-init per tile.
__global__ __launch_bounds__(256) void attn_kernel(
        const unsigned short* __restrict__ qg, const unsigned short* __restrict__ kg,
        const unsigned short* __restrict__ vg, unsigned short* __restrict__ ao) {
    int bid = blockIdx.x;
    int nh = bid & 127, qbk = bid >> 7;     // 8 q-blocks of one head share an XCD
    int tid = threadIdx.x, w = tid >> 6, lane = tid & 63;
    int lq = lane & 31, hi = lane >> 5;
    const unsigned short* Q = qg + (size_t)nh * 65536;
    const unsigned short* K = kg + (size_t)nh * 65536;
    const unsigned short* V = vg + (size_t)nh * 65536;   // [d][t]

    __shared__ unsigned short Klds[2][64*72];            // [t][d], pad 8
    __shared__ unsigned short Vlds[2][64*72];            // [d][t], pad 8

    int q0 = qbk*128 + w*32;
    bf16x8 qf[4];
    #pragma unroll
    for (int ks = 0; ks < 4; ks++)
        qf[ks] = *(const bf16x8*)(Q + ((size_t)(q0 + lq))*64 + ks*16 + hi*8);

    // staging: each thread owns 32B of K-tile and V-tile
    int r = tid >> 2, part = (tid & 3) * 16;
    uint4 ka, kb2, va, vb2;
    ka  = *(const uint4*)(K + (size_t)r*64 + part);
    kb2 = *(const uint4*)(K + (size_t)r*64 + part + 8);
    va  = *(const uint4*)(V + (size_t)r*1024 + part);
    vb2 = *(const uint4*)(V + (size_t)r*1024 + part + 8);

    // all-ones bf16 B operand (layout-irrelevant: every element is 1.0)
    const bf16x8 ONES = mk8(0x3f803f80u, 0x3f803f80u, 0x3f803f80u, 0x3f803f80u);

    f32x16v O0, O1, Os, ZED;
    #pragma unroll
    for (int i = 0; i < 16; i++) { O0[i] = 0.f; O1[i] = 0.f; Os[i] = 0.f; ZED[i] = 0.f; }

    for (int it = 0; it < 16; it++) {
        int buf = it & 1;
        {   // commit staged regs to LDS
            unsigned short* kd = Klds[buf] + r*72 + part;
            *(uint4*)kd = ka; *(uint4*)(kd+8) = kb2;
            unsigned short* vd = Vlds[buf] + r*72 + part;
            *(uint4*)vd = va; *(uint4*)(vd+8) = vb2;
        }
        __syncthreads();
        if (it < 15) {   // prefetch next tile (overlaps compute below)
            int t0 = (it + 1) * 64;
            ka  = *(const uint4*)(K + (size_t)(t0 + r)*64 + part);
            kb2 = *(const uint4*)(K + (size_t)(t0 + r)*64 + part + 8);
            va  = *(const uint4*)(V + (size_t)r*1024 + t0 + part);
            vb2 = *(const uint4*)(V + (size_t)r*1024 + t0 + part + 8);
        }
        const unsigned short* Kb = Klds[buf];
        const unsigned short* Vb = Vlds[buf];

        // first ks uses ZED as C (no per-tile zero-init movs)
        f32x16v S0, S1;
        {
            bf16x8 a0 = *(const bf16x8*)(Kb + lq*72 + hi*8);
            bf16x8 a1 = *(const bf16x8*)(Kb + (32+lq)*72 + hi*8);
            S0 = __builtin_amdgcn_mfma_f32_32x32x16_bf16(a0, qf[0], ZED, 0, 0, 0);
            S1 = __builtin_amdgcn_mfma_f32_32x32x16_bf16(a1, qf[0], ZED, 0, 0, 0);
        }
        #pragma unroll
        for (int ks = 1; ks < 4; ks++) {
            bf16x8 a0 = *(const bf16x8*)(Kb + lq*72 + ks*16 + hi*8);
            bf16x8 a1 = *(const bf16x8*)(Kb + (32+lq)*72 + ks*16 + hi*8);
            S0 = __builtin_amdgcn_mfma_f32_32x32x16_bf16(a0, qf[ks], S0, 0, 0, 0);
            S1 = __builtin_amdgcn_mfma_f32_32x32x16_bf16(a1, qf[ks], S1, 0, 0, 0);
        }

        // p = exp2(S) via bare v_exp_f32
        #pragma unroll
        for (int i = 0; i < 16; i++) {
            S0[i] = fexp2(S0[i]);
            S1[i] = fexp2(S1[i]);
        }
        unsigned d[16];
        #pragma unroll
        for (int p2 = 0; p2 < 8; p2++) {
            d[p2]     = pk2bf_rne(S0[p2*2], S0[p2*2+1]);
            d[8 + p2] = pk2bf_rne(S1[p2*2], S1[p2*2+1]);
        }
        // in-register C->A transform: swap(d0,d2)->(A0,A2), swap(d1,d3)->(A1,A3)
        swap32(d[0],  d[2]);  swap32(d[1],  d[3]);
        swap32(d[4],  d[6]);  swap32(d[5],  d[7]);
        swap32(d[8],  d[10]); swap32(d[9],  d[11]);
        swap32(d[12], d[14]); swap32(d[13], d[15]);

        #pragma unroll
        for (int kc = 0; kc < 4; kc++) {
            bf16x8 pa = mk8(d[kc*4+0], d[kc*4+1], d[kc*4+2], d[kc*4+3]);
            bf16x8 v0 = *(const bf16x8*)(Vb + lq*72 + kc*16 + hi*8);
            bf16x8 v1 = *(const bf16x8*)(Vb + (32+lq)*72 + kc*16 + hi*8);
            O0 = __builtin_amdgcn_mfma_f32_32x32x16_bf16(pa, v0, O0, 0, 0, 0);
            O1 = __builtin_amdgcn_mfma_f32_32x32x16_bf16(pa, v1, O1, 0, 0, 0);
            Os = __builtin_amdgcn_mfma_f32_32x32x16_bf16(pa, ONES, Os, 0, 0, 0);
        }
    }

    // Os[reg] = sum_t P[t][q(reg-row)] (all 32 columns identical) -> lane-local
    int n = nh >> 3, h = nh & 7;
    #pragma unroll
    for (int rq = 0; rq < 4; rq++) {
        #pragma unroll
        for (int i = 0; i < 4; i++) {
            int reg = rq*4 + i;
            int sQ = q0 + rq*8 + hi*4 + i;
            float inv = frcp(Os[reg]);
            size_t rowb = ((size_t)(n*1024 + sQ))*512 + h*64;
            ao[rowb + lq]      = (unsigned short)f2bf_rn(O0[reg] * inv);
            ao[rowb + 32 + lq] = (unsigned short)f2bf_rn(O1[reg] * inv);
        }
    }
}

// ---------------- out GEMM: D[s][d] = sum_c aoT[s][c]*WoT[d][c]; +bias+x ----------------
__global__ __launch_bounds__(256) void out_kernel(
        const unsigned short* __restrict__ aoT, const unsigned short* __restrict__ WoT,
        const float* __restrict__ bout, const float* __restrict__ x,
        float* __restrict__ out) {
    int s0 = blockIdx.x * 128, d0b = blockIdx.y * 128, n = blockIdx.z;
    __shared__ unsigned short At[4096];
    __shared__ unsigned short Bt[4096];
    int tid = threadIdx.x;
    int lane = tid & 63, w = tid >> 6;
    int quad = lane >> 4, tx = lane & 15;
    int moff = (w & 1) * 64, noff = (w >> 1) * 64;

    const unsigned short* Arow = aoT + ((size_t)n * 1024 + s0) * 512;
    const unsigned short* Brow = WoT + (size_t)d0b * 512;

    f32x4v acc[4][4];
    #pragma unroll
    for (int i = 0; i < 4; i++)
        #pragma unroll
        for (int j = 0; j < 4; j++)
            #pragma unroll
            for (int e = 0; e < 4; e++) acc[i][j][e] = 0.f;

    int f1 = tid, f2 = tid + 256;
    int m1 = f1 >> 2, kb1 = ((f1 & 3) - (f1 >> 3)) & 3;
    int m2 = f2 >> 2, kb2 = ((f2 & 3) - (f2 >> 3)) & 3;

    for (int k0 = 0; k0 < 512; k0 += 32) {
        __syncthreads();
        GLD_LDS16(Arow + (size_t)m1*512 + k0 + kb1*8, At + f1*8);
        GLD_LDS16(Arow + (size_t)m2*512 + k0 + kb2*8, At + f2*8);
        GLD_LDS16(Brow + (size_t)m1*512 + k0 + kb1*8, Bt + f1*8);
        GLD_LDS16(Brow + (size_t)m2*512 + k0 + kb2*8, Bt + f2*8);
        __syncthreads();
        bf16x8 af[4], bfr[4];
        #pragma unroll
        for (int mt = 0; mt < 4; mt++) {
            int m = moff + mt*16 + tx;
            int ch = m*4 + ((quad + (m >> 1)) & 3);
            af[mt] = *(const bf16x8*)(At + ch*8);
        }
        #pragma unroll
        for (int nt = 0; nt < 4; nt++) {
            int m = noff + nt*16 + tx;
            int ch = m*4 + ((quad + (m >> 1)) & 3);
            bfr[nt] = *(const bf16x8*)(Bt + ch*8);
        }
        #pragma unroll
        for (int mt = 0; mt < 4; mt++)
            #pragma unroll
            for (int nt = 0; nt < 4; nt++)
                acc[mt][nt] = __builtin_amdgcn_mfma_f32_16x16x32_bf16(
                    af[mt], bfr[nt], acc[mt][nt], 0, 0, 0);
    }

    #pragma unroll
    for (int mt = 0; mt < 4; mt++) {
        int sQ = s0 + moff + mt*16 + quad*4;
        #pragma unroll
        for (int nt = 0; nt < 4; nt++) {
            int d = d0b + noff + nt*16 + tx;
            float bo = bout[d];
            size_t base = ((size_t)n*512 + d)*1024 + sQ;
            float4 xv = *(const float4*)(x + base);
            f32x4v a = acc[mt][nt];
            float4 o = make_float4(a[0]+bo+xv.x, a[1]+bo+xv.y, a[2]+bo+xv.z, a[3]+bo+xv.w);
            *(float4*)(out + base) = o;
        }
    }
}

extern "C" void kernel_launch(void* const* d_in, const int* in_sizes, int n_in,
                              void* d_out, int out_size, void* d_ws, size_t ws_size,
                              hipStream_t stream) {
    const float* x    = (const float*)d_in[0];
    const float* gns  = (const float*)d_in[1];
    const float* gnb  = (const float*)d_in[2];
    const float* wqkv = (const float*)d_in[3];
    const float* bqkv = (const float*)d_in[4];
    const float* wout = (const float*)d_in[5];
    const float* bout = (const float*)d_in[6];
    float* out = (float*)d_out;

    char* p = (char*)d_ws;
    size_t off = 0;
    auto carve = [&](size_t bytes) {
        char* r = p + off;
        off = (off + bytes + 255) & ~(size_t)255;
        return r;
    };
    unsigned short* hnT = (unsigned short*)carve((size_t)16*1024*512*2);
    unsigned short* qb2 = (unsigned short*)carve((size_t)128*1024*64*2);
    unsigned short* kb2 = (unsigned short*)carve((size_t)128*1024*64*2);
    unsigned short* vb2 = (unsigned short*)carve((size_t)128*64*1024*2);
    unsigned short* aoT = (unsigned short*)carve((size_t)16*1024*512*2);
    unsigned short* WqT = (unsigned short*)carve((size_t)1536*512*2);
    unsigned short* WoT = (unsigned short*)carve((size_t)512*512*2);

    wt_kernel<<<dim3(64, 16), 256, 0, stream>>>(wqkv, wout, WqT, WoT);
    gn_kernel<<<dim3(512), 256, 0, stream>>>(x, gns, gnb, hnT);
    qkv_kernel<<<dim3(8, 12, 16), 256, 0, stream>>>(WqT, hnT, bqkv, qb2, kb2, vb2);
    attn_kernel<<<dim3(1024), 256, 0, stream>>>(qb2, kb2, vb2, aoT);
    out_kernel<<<dim3(8, 4, 16), 256, 0, stream>>>(aoT, WoT, bout, x, out);
}

// Round 4
// 206.145 us; speedup vs baseline: 1.1780x; 1.0123x over previous
//
#include <hip/hip_runtime.h>
#include <stdint.h>

typedef __bf16 bf16x8 __attribute__((ext_vector_type(8)));
typedef float f32x4v __attribute__((ext_vector_type(4)));
typedef float f32x16v __attribute__((ext_vector_type(16)));
typedef unsigned u32x2 __attribute__((ext_vector_type(2)));

// round-to-nearest bf16 (2 ops)
__device__ __forceinline__ unsigned f2bf_rn(float f) {
    return (__float_as_uint(f) + 0x8000u) >> 16;
}
// pack two floats -> two bf16 in one dword: 2 adds + 1 v_perm
__device__ __forceinline__ unsigned pk2bf(float a, float b) {
    return __builtin_amdgcn_perm(__float_as_uint(b) + 0x8000u,
                                 __float_as_uint(a) + 0x8000u, 0x07060302u);
}
// pack two floats -> two bf16 via HW v_cvt_pk_bf16_f32 (RNE).
__device__ __forceinline__ unsigned pk2bf_rne(float a, float b) {
    union { __bf16 h[2]; unsigned u; } x;
    x.h[0] = (__bf16)a; x.h[1] = (__bf16)b;
    return x.u;
}
// raw v_exp_f32: logits bounded (|x| << 126) so the LLVM denorm-guard
// sequence (~5 VALU ops) around llvm.exp2.f32 is pure waste.
__device__ __forceinline__ float fexp2(float x) {
#if __has_builtin(__builtin_amdgcn_exp2f)
    return __builtin_amdgcn_exp2f(x);
#else
    float r; asm volatile("v_exp_f32 %0, %1" : "=v"(r) : "v"(x)); return r;
#endif
}
// raw v_rcp_f32 (~1 ulp): fine for softmax denominator.
__device__ __forceinline__ float frcp(float x) {
#if __has_builtin(__builtin_amdgcn_rcpf)
    return __builtin_amdgcn_rcpf(x);
#else
    float r; asm volatile("v_rcp_f32 %0, %1" : "=v"(r) : "v"(x)); return r;
#endif
}

// swap a.hi32lanes <-> b.lo32lanes (gfx950 v_permlane32_swap_b32)
__device__ __forceinline__ void swap32(unsigned &a, unsigned &b) {
#if __has_builtin(__builtin_amdgcn_permlane32_swap)
    u32x2 r = __builtin_amdgcn_permlane32_swap(a, b, false, false);
    a = r[0]; b = r[1];
#else
    unsigned pa = (unsigned)__shfl_xor((int)a, 32);
    unsigned pb = (unsigned)__shfl_xor((int)b, 32);
    bool hi = (threadIdx.x & 32) != 0;
    unsigned na = hi ? pb : a;
    unsigned nb = hi ? b : pa;
    a = na; b = nb;
#endif
}

__device__ __forceinline__ bf16x8 mk8(unsigned a, unsigned b, unsigned c, unsigned e) {
    union { int4 i; bf16x8 v; } u;
    u.i = make_int4((int)a, (int)b, (int)c, (int)e);
    return u.v;
}

#define GLD_LDS16(gp, lp) __builtin_amdgcn_global_load_lds( \
    (const __attribute__((address_space(1))) unsigned int*)(gp), \
    (__attribute__((address_space(3))) unsigned int*)(lp), 16, 0, 0)

// ---------------- weight transposes (both matrices, one launch) ----------------
__global__ __launch_bounds__(256) void wt_kernel(const float* __restrict__ wqkv,
        const float* __restrict__ wout, unsigned short* __restrict__ WqT,
        unsigned short* __restrict__ WoT) {
    __shared__ float tile[32][33];
    int bx = blockIdx.x;
    const float* in; unsigned short* out; int Cc, c0;
    if (bx < 48) { in = wqkv; out = WqT; Cc = 1536; c0 = bx * 32; }
    else         { in = wout; out = WoT; Cc = 512;  c0 = (bx - 48) * 32; }
    int r0 = blockIdx.y * 32;
    int tx = threadIdx.x & 31, ty = threadIdx.x >> 5;
    #pragma unroll
    for (int i = 0; i < 4; i++) {
        int r = ty + i * 8;
        tile[r][tx] = in[(size_t)(r0 + r) * Cc + c0 + tx];
    }
    __syncthreads();
    #pragma unroll
    for (int i = 0; i < 4; i++) {
        int cr = ty + i * 8;
        out[(size_t)(c0 + cr) * 512 + r0 + tx] = (unsigned short)f2bf_rn(tile[tx][cr]);
    }
}

// ---------------- GroupNorm -> hnT bf16 [n][s][c] ----------------
// Single-pass: the 64 KB group-slab persists in LDS (grid = 2 blocks/CU, so
// 68 KB/block costs no occupancy); normalize pass reads LDS, not global.
__global__ __launch_bounds__(256) void gn_kernel(const float* __restrict__ x,
        const float* __restrict__ scale, const float* __restrict__ bias,
        unsigned short* __restrict__ hnT) {
    int blk = blockIdx.x;                  // n*32+g
    int tid = threadIdx.x;
    int g = blk & 31, n = blk >> 5;
    const float4* src4 = (const float4*)(x + (size_t)blk * 16384);

    __shared__ float xs[16][1028];         // 16 ch x 1024 px, +4 pad
    float s = 0.f, s2 = 0.f;
    #pragma unroll
    for (int k = 0; k < 16; k++) {
        int i = tid + k * 256;
        float4 v = src4[i];
        int c = i >> 8, p4 = (i & 255) * 4;
        *(float4*)&xs[c][p4] = v;
        s  += v.x + v.y + v.z + v.w;
        s2 += v.x*v.x + v.y*v.y + v.z*v.z + v.w*v.w;
    }
    __shared__ float red[256], red2[256];
    red[tid] = s; red2[tid] = s2;
    __syncthreads();
    for (int off = 128; off > 0; off >>= 1) {
        if (tid < off) { red[tid] += red[tid+off]; red2[tid] += red2[tid+off]; }
        __syncthreads();
    }
    __shared__ float sc_s[16], bi_s[16];
    if (tid < 16) {
        float mean = red[0] * (1.f/16384.f);
        float var  = red2[0] * (1.f/16384.f) - mean*mean;
        float rstd = rsqrtf(var + 1e-6f);
        int c = g*16 + tid;
        float sc = scale[c] * rstd;
        sc_s[tid] = sc;
        bi_s[tid] = bias[c] - mean * sc;
    }
    __syncthreads();
    #pragma unroll
    for (int ch = 0; ch < 4; ch++) {
        int sQ = ch*256 + tid;
        unsigned int pk[8];
        #pragma unroll
        for (int c2 = 0; c2 < 8; c2++) {
            float a = xs[c2*2][sQ]   * sc_s[c2*2]   + bi_s[c2*2];
            float b = xs[c2*2+1][sQ] * sc_s[c2*2+1] + bi_s[c2*2+1];
            pk[c2] = pk2bf(a, b);
        }
        unsigned short* op = hnT + ((size_t)(n*1024 + sQ))*512 + g*16;
        *(uint4*)op       = make_uint4(pk[0], pk[1], pk[2], pk[3]);
        *((uint4*)op + 1) = make_uint4(pk[4], pk[5], pk[6], pk[7]);
    }
}

// ---------------- QKV GEMM: D[m][s] = sum_c WqT[m][c]*hnT[s][c] ----------------
// BK=64 per barrier phase (two 32-k sub-tiles): halves barrier-drain count.
__global__ __launch_bounds__(256) void qkv_kernel(
        const unsigned short* __restrict__ WqT, const unsigned short* __restrict__ hnT,
        const float* __restrict__ bqkv,
        unsigned short* __restrict__ qb, unsigned short* __restrict__ kbuf,
        unsigned short* __restrict__ vb) {
    int s0 = blockIdx.x * 128, m0 = blockIdx.y * 128, n = blockIdx.z;
    __shared__ unsigned short At[8192];    // 2 x (128 rows x 32 c), swizzled 16B chunks
    __shared__ unsigned short Bt[8192];
    int tid = threadIdx.x;
    int lane = tid & 63, w = tid >> 6;
    int quad = lane >> 4, tx = lane & 15;
    int moff = (w & 1) * 64, soff = (w >> 1) * 64;

    const unsigned short* Arow = WqT + (size_t)m0 * 512;
    const unsigned short* Brow = hnT + ((size_t)n * 1024 + s0) * 512;

    f32x4v acc[4][4];
    #pragma unroll
    for (int i = 0; i < 4; i++)
        #pragma unroll
        for (int j = 0; j < 4; j++)
            #pragma unroll
            for (int e = 0; e < 4; e++) acc[i][j][e] = 0.f;

    int f1 = tid, f2 = tid + 256;
    int m1 = f1 >> 2, kb1 = ((f1 & 3) - (f1 >> 3)) & 3;
    int m2 = f2 >> 2, kb2 = ((f2 & 3) - (f2 >> 3)) & 3;

    for (int k0 = 0; k0 < 512; k0 += 64) {
        __syncthreads();
        GLD_LDS16(Arow + (size_t)m1*512 + k0 + kb1*8,      At + f1*8);
        GLD_LDS16(Arow + (size_t)m2*512 + k0 + kb2*8,      At + f2*8);
        GLD_LDS16(Arow + (size_t)m1*512 + k0 + 32 + kb1*8, At + 4096 + f1*8);
        GLD_LDS16(Arow + (size_t)m2*512 + k0 + 32 + kb2*8, At + 4096 + f2*8);
        GLD_LDS16(Brow + (size_t)m1*512 + k0 + kb1*8,      Bt + f1*8);
        GLD_LDS16(Brow + (size_t)m2*512 + k0 + kb2*8,      Bt + f2*8);
        GLD_LDS16(Brow + (size_t)m1*512 + k0 + 32 + kb1*8, Bt + 4096 + f1*8);
        GLD_LDS16(Brow + (size_t)m2*512 + k0 + 32 + kb2*8, Bt + 4096 + f2*8);
        __syncthreads();
        #pragma unroll
        for (int kk = 0; kk < 2; kk++) {
            const unsigned short* Ab = At + kk*4096;
            const unsigned short* Bb = Bt + kk*4096;
            bf16x8 af[4], bfr[4];
            #pragma unroll
            for (int mt = 0; mt < 4; mt++) {
                int m = moff + mt*16 + tx;
                int ch = m*4 + ((quad + (m >> 1)) & 3);
                af[mt] = *(const bf16x8*)(Ab + ch*8);
            }
            #pragma unroll
            for (int nt = 0; nt < 4; nt++) {
                int m = soff + nt*16 + tx;
                int ch = m*4 + ((quad + (m >> 1)) & 3);
                bfr[nt] = *(const bf16x8*)(Bb + ch*8);
            }
            #pragma unroll
            for (int mt = 0; mt < 4; mt++)
                #pragma unroll
                for (int nt = 0; nt < 4; nt++)
                    acc[mt][nt] = __builtin_amdgcn_mfma_f32_16x16x32_bf16(
                        af[mt], bfr[nt], acc[mt][nt], 0, 0, 0);
        }
    }

    // Epilogue: q scaled by 0.125*log2(e) (exp2-domain softmax downstream).
    const float QSCL = 0.18033688011112042f;
    #pragma unroll
    for (int mt = 0; mt < 4; mt++) {
        int m = m0 + moff + mt*16 + quad*4;
        int head = m / 192;
        int r = m - head*192;
        int which = r >> 6;
        int d0 = r & 63;
        float4 bia = *(const float4*)(bqkv + m);
        float scl = (which == 0) ? QSCL : 1.0f;
        #pragma unroll
        for (int nt = 0; nt < 4; nt++) {
            int sQ = s0 + soff + nt*16 + tx;
            f32x4v a = acc[mt][nt];
            float v0 = (a[0]+bia.x)*scl, v1 = (a[1]+bia.y)*scl;
            float v2 = (a[2]+bia.z)*scl, v3 = (a[3]+bia.w)*scl;
            if (which < 2) {
                unsigned short* base = (which == 0) ? qb : kbuf;
                unsigned lo = pk2bf(v0, v1), hi2 = pk2bf(v2, v3);
                *(uint2*)(base + (((size_t)(n*8 + head)*1024 + sQ) << 6) + d0) =
                    make_uint2(lo, hi2);
            } else {
                size_t vbase = ((size_t)(n*8 + head)*64 + d0)*1024 + sQ;
                vb[vbase]        = (unsigned short)f2bf_rn(v0);
                vb[vbase + 1024] = (unsigned short)f2bf_rn(v1);
                vb[vbase + 2048] = (unsigned short)f2bf_rn(v2);
                vb[vbase + 3072] = (unsigned short)f2bf_rn(v3);
            }
        }
    }
}

// ---------------- flash attention: in-register P transpose, pipelined staging ----
// Fixed-max exp2 softmax (logits are 0.18*(q.k), |logit| << 127 so no overflow).
// S^T = K*Q^T gives C-layout col=q, row=t; 4 permlane32_swap per 32-t block
// converts packed P dwords directly to the PV A-operand layout (no LDS trip).
// Softmax denominator on the MFMA pipe (Osum = P @ ones, lane-local epilogue).
// Persistent ZED C-operand avoids per-tile S-init movs.
__global__ __launch_bounds__(256) void attn_kernel(
        const unsigned short* __restrict__ qg, const unsigned short* __restrict__ kg,
        const unsigned short* __restrict__ vg, unsigned short* __restrict__ ao) {
    int bid = blockIdx.x;
    int nh = bid & 127, qbk = bid >> 7;     // 8 q-blocks of one head share an XCD
    int tid = threadIdx.x, w = tid >> 6, lane = tid & 63;
    int lq = lane & 31, hi = lane >> 5;
    const unsigned short* Q = qg + (size_t)nh * 65536;
    const unsigned short* K = kg + (size_t)nh * 65536;
    const unsigned short* V = vg + (size_t)nh * 65536;   // [d][t]

    __shared__ unsigned short Klds[2][64*72];            // [t][d], pad 8
    __shared__ unsigned short Vlds[2][64*72];            // [d][t], pad 8

    int q0 = qbk*128 + w*32;
    bf16x8 qf[4];
    #pragma unroll
    for (int ks = 0; ks < 4; ks++)
        qf[ks] = *(const bf16x8*)(Q + ((size_t)(q0 + lq))*64 + ks*16 + hi*8);

    // staging: each thread owns 32B of K-tile and V-tile
    int r = tid >> 2, part = (tid & 3) * 16;
    uint4 ka, kb2, va, vb2;
    ka  = *(const uint4*)(K + (size_t)r*64 + part);
    kb2 = *(const uint4*)(K + (size_t)r*64 + part + 8);
    va  = *(const uint4*)(V + (size_t)r*1024 + part);
    vb2 = *(const uint4*)(V + (size_t)r*1024 + part + 8);

    // all-ones bf16 B operand (layout-irrelevant: every element is 1.0)
    const bf16x8 ONES = mk8(0x3f803f80u, 0x3f803f80u, 0x3f803f80u, 0x3f803f80u);

    f32x16v O0, O1, Os, ZED;
    #pragma unroll
    for (int i = 0; i < 16; i++) { O0[i] = 0.f; O1[i] = 0.f; Os[i] = 0.f; ZED[i] = 0.f; }

    for (int it = 0; it < 16; it++) {
        int buf = it & 1;
        {   // commit staged regs to LDS
            unsigned short* kd = Klds[buf] + r*72 + part;
            *(uint4*)kd = ka; *(uint4*)(kd+8) = kb2;
            unsigned short* vd = Vlds[buf] + r*72 + part;
            *(uint4*)vd = va; *(uint4*)(vd+8) = vb2;
        }
        __syncthreads();
        if (it < 15) {   // prefetch next tile (overlaps compute below)
            int t0 = (it + 1) * 64;
            ka  = *(const uint4*)(K + (size_t)(t0 + r)*64 + part);
            kb2 = *(const uint4*)(K + (size_t)(t0 + r)*64 + part + 8);
            va  = *(const uint4*)(V + (size_t)r*1024 + t0 + part);
            vb2 = *(const uint4*)(V + (size_t)r*1024 + t0 + part + 8);
        }
        const unsigned short* Kb = Klds[buf];
        const unsigned short* Vb = Vlds[buf];

        // first ks uses ZED as C (no per-tile zero-init movs)
        f32x16v S0, S1;
        {
            bf16x8 a0 = *(const bf16x8*)(Kb + lq*72 + hi*8);
            bf16x8 a1 = *(const bf16x8*)(Kb + (32+lq)*72 + hi*8);
            S0 = __builtin_amdgcn_mfma_f32_32x32x16_bf16(a0, qf[0], ZED, 0, 0, 0);
            S1 = __builtin_amdgcn_mfma_f32_32x32x16_bf16(a1, qf[0], ZED, 0, 0, 0);
        }
        #pragma unroll
        for (int ks = 1; ks < 4; ks++) {
            bf16x8 a0 = *(const bf16x8*)(Kb + lq*72 + ks*16 + hi*8);
            bf16x8 a1 = *(const bf16x8*)(Kb + (32+lq)*72 + ks*16 + hi*8);
            S0 = __builtin_amdgcn_mfma_f32_32x32x16_bf16(a0, qf[ks], S0, 0, 0, 0);
            S1 = __builtin_amdgcn_mfma_f32_32x32x16_bf16(a1, qf[ks], S1, 0, 0, 0);
        }

        // p = exp2(S) via bare v_exp_f32
        #pragma unroll
        for (int i = 0; i < 16; i++) {
            S0[i] = fexp2(S0[i]);
            S1[i] = fexp2(S1[i]);
        }
        unsigned d[16];
        #pragma unroll
        for (int p2 = 0; p2 < 8; p2++) {
            d[p2]     = pk2bf_rne(S0[p2*2], S0[p2*2+1]);
            d[8 + p2] = pk2bf_rne(S1[p2*2], S1[p2*2+1]);
        }
        // in-register C->A transform: swap(d0,d2)->(A0,A2), swap(d1,d3)->(A1,A3)
        swap32(d[0],  d[2]);  swap32(d[1],  d[3]);
        swap32(d[4],  d[6]);  swap32(d[5],  d[7]);
        swap32(d[8],  d[10]); swap32(d[9],  d[11]);
        swap32(d[12], d[14]); swap32(d[13], d[15]);

        #pragma unroll
        for (int kc = 0; kc < 4; kc++) {
            bf16x8 pa = mk8(d[kc*4+0], d[kc*4+1], d[kc*4+2], d[kc*4+3]);
            bf16x8 v0 = *(const bf16x8*)(Vb + lq*72 + kc*16 + hi*8);
            bf16x8 v1 = *(const bf16x8*)(Vb + (32+lq)*72 + kc*16 + hi*8);
            O0 = __builtin_amdgcn_mfma_f32_32x32x16_bf16(pa, v0, O0, 0, 0, 0);
            O1 = __builtin_amdgcn_mfma_f32_32x32x16_bf16(pa, v1, O1, 0, 0, 0);
            Os = __builtin_amdgcn_mfma_f32_32x32x16_bf16(pa, ONES, Os, 0, 0, 0);
        }
    }

    // Os[reg] = sum_t P[t][q(reg-row)] (all 32 columns identical) -> lane-local
    int n = nh >> 3, h = nh & 7;
    #pragma unroll
    for (int rq = 0; rq < 4; rq++) {
        #pragma unroll
        for (int i = 0; i < 4; i++) {
            int reg = rq*4 + i;
            int sQ = q0 + rq*8 + hi*4 + i;
            float inv = frcp(Os[reg]);
            size_t rowb = ((size_t)(n*1024 + sQ))*512 + h*64;
            ao[rowb + lq]      = (unsigned short)f2bf_rn(O0[reg] * inv);
            ao[rowb + 32 + lq] = (unsigned short)f2bf_rn(O1[reg] * inv);
        }
    }
}

// ---------------- out GEMM: D[s][d] = sum_c aoT[s][c]*WoT[d][c]; +bias+x ----------------
// BK=64 per barrier phase (two 32-k sub-tiles): halves barrier-drain count.
__global__ __launch_bounds__(256) void out_kernel(
        const unsigned short* __restrict__ aoT, const unsigned short* __restrict__ WoT,
        const float* __restrict__ bout, const float* __restrict__ x,
        float* __restrict__ out) {
    int s0 = blockIdx.x * 128, d0b = blockIdx.y * 128, n = blockIdx.z;
    __shared__ unsigned short At[8192];
    __shared__ unsigned short Bt[8192];
    int tid = threadIdx.x;
    int lane = tid & 63, w = tid >> 6;
    int quad = lane >> 4, tx = lane & 15;
    int moff = (w & 1) * 64, noff = (w >> 1) * 64;

    const unsigned short* Arow = aoT + ((size_t)n * 1024 + s0) * 512;
    const unsigned short* Brow = WoT + (size_t)d0b * 512;

    f32x4v acc[4][4];
    #pragma unroll
    for (int i = 0; i < 4; i++)
        #pragma unroll
        for (int j = 0; j < 4; j++)
            #pragma unroll
            for (int e = 0; e < 4; e++) acc[i][j][e] = 0.f;

    int f1 = tid, f2 = tid + 256;
    int m1 = f1 >> 2, kb1 = ((f1 & 3) - (f1 >> 3)) & 3;
    int m2 = f2 >> 2, kb2 = ((f2 & 3) - (f2 >> 3)) & 3;

    for (int k0 = 0; k0 < 512; k0 += 64) {
        __syncthreads();
        GLD_LDS16(Arow + (size_t)m1*512 + k0 + kb1*8,      At + f1*8);
        GLD_LDS16(Arow + (size_t)m2*512 + k0 + kb2*8,      At + f2*8);
        GLD_LDS16(Arow + (size_t)m1*512 + k0 + 32 + kb1*8, At + 4096 + f1*8);
        GLD_LDS16(Arow + (size_t)m2*512 + k0 + 32 + kb2*8, At + 4096 + f2*8);
        GLD_LDS16(Brow + (size_t)m1*512 + k0 + kb1*8,      Bt + f1*8);
        GLD_LDS16(Brow + (size_t)m2*512 + k0 + kb2*8,      Bt + f2*8);
        GLD_LDS16(Brow + (size_t)m1*512 + k0 + 32 + kb1*8, Bt + 4096 + f1*8);
        GLD_LDS16(Brow + (size_t)m2*512 + k0 + 32 + kb2*8, Bt + 4096 + f2*8);
        __syncthreads();
        #pragma unroll
        for (int kk = 0; kk < 2; kk++) {
            const unsigned short* Ab = At + kk*4096;
            const unsigned short* Bb = Bt + kk*4096;
            bf16x8 af[4], bfr[4];
            #pragma unroll
            for (int mt = 0; mt < 4; mt++) {
                int m = moff + mt*16 + tx;
                int ch = m*4 + ((quad + (m >> 1)) & 3);
                af[mt] = *(const bf16x8*)(Ab + ch*8);
            }
            #pragma unroll
            for (int nt = 0; nt < 4; nt++) {
                int m = noff + nt*16 + tx;
                int ch = m*4 + ((quad + (m >> 1)) & 3);
                bfr[nt] = *(const bf16x8*)(Bb + ch*8);
            }
            #pragma unroll
            for (int mt = 0; mt < 4; mt++)
                #pragma unroll
                for (int nt = 0; nt < 4; nt++)
                    acc[mt][nt] = __builtin_amdgcn_mfma_f32_16x16x32_bf16(
                        af[mt], bfr[nt], acc[mt][nt], 0, 0, 0);
        }
    }

    #pragma unroll
    for (int mt = 0; mt < 4; mt++) {
        int sQ = s0 + moff + mt*16 + quad*4;
        #pragma unroll
        for (int nt = 0; nt < 4; nt++) {
            int d = d0b + noff + nt*16 + tx;
            float bo = bout[d];
            size_t base = ((size_t)n*512 + d)*1024 + sQ;
            float4 xv = *(const float4*)(x + base);
            f32x4v a = acc[mt][nt];
            float4 o = make_float4(a[0]+bo+xv.x, a[1]+bo+xv.y, a[2]+bo+xv.z, a[3]+bo+xv.w);
            *(float4*)(out + base) = o;
        }
    }
}

extern "C" void kernel_launch(void* const* d_in, const int* in_sizes, int n_in,
                              void* d_out, int out_size, void* d_ws, size_t ws_size,
                              hipStream_t stream) {
    const float* x    = (const float*)d_in[0];
    const float* gns  = (const float*)d_in[1];
    const float* gnb  = (const float*)d_in[2];
    const float* wqkv = (const float*)d_in[3];
    const float* bqkv = (const float*)d_in[4];
    const float* wout = (const float*)d_in[5];
    const float* bout = (const float*)d_in[6];
    float* out = (float*)d_out;

    char* p = (char*)d_ws;
    size_t off = 0;
    auto carve = [&](size_t bytes) {
        char* r = p + off;
        off = (off + bytes + 255) & ~(size_t)255;
        return r;
    };
    unsigned short* hnT = (unsigned short*)carve((size_t)16*1024*512*2);
    unsigned short* qb2 = (unsigned short*)carve((size_t)128*1024*64*2);
    unsigned short* kb2 = (unsigned short*)carve((size_t)128*1024*64*2);
    unsigned short* vb2 = (unsigned short*)carve((size_t)128*64*1024*2);
    unsigned short* aoT = (unsigned short*)carve((size_t)16*1024*512*2);
    unsigned short* WqT = (unsigned short*)carve((size_t)1536*512*2);
    unsigned short* WoT = (unsigned short*)carve((size_t)512*512*2);

    wt_kernel<<<dim3(64, 16), 256, 0, stream>>>(wqkv, wout, WqT, WoT);
    gn_kernel<<<dim3(512), 256, 0, stream>>>(x, gns, gnb, hnT);
    qkv_kernel<<<dim3(8, 12, 16), 256, 0, stream>>>(WqT, hnT, bqkv, qb2, kb2, vb2);
    attn_kernel<<<dim3(1024), 256, 0, stream>>>(qb2, kb2, vb2, aoT);
    out_kernel<<<dim3(8, 4, 16), 256, 0, stream>>>(aoT, WoT, bout, x, out);
}

// Round 6
// 198.032 us; speedup vs baseline: 1.2263x; 1.0410x over previous
//
#include <hip/hip_runtime.h>
#include <stdint.h>

typedef __bf16 bf16x8 __attribute__((ext_vector_type(8)));
typedef float f32x4v __attribute__((ext_vector_type(4)));
typedef float f32x16v __attribute__((ext_vector_type(16)));
typedef unsigned u32x2 __attribute__((ext_vector_type(2)));

// round-to-nearest bf16 (2 ops)
__device__ __forceinline__ unsigned f2bf_rn(float f) {
    return (__float_as_uint(f) + 0x8000u) >> 16;
}
// pack two floats -> two bf16 in one dword: 2 adds + 1 v_perm
__device__ __forceinline__ unsigned pk2bf(float a, float b) {
    return __builtin_amdgcn_perm(__float_as_uint(b) + 0x8000u,
                                 __float_as_uint(a) + 0x8000u, 0x07060302u);
}
// pack two floats -> two bf16 via HW v_cvt_pk_bf16_f32 (RNE).
__device__ __forceinline__ unsigned pk2bf_rne(float a, float b) {
    union { __bf16 h[2]; unsigned u; } x;
    x.h[0] = (__bf16)a; x.h[1] = (__bf16)b;
    return x.u;
}
// raw v_exp_f32: logits bounded (|x| << 126) so the LLVM denorm-guard
// sequence (~5 VALU ops) around llvm.exp2.f32 is pure waste.
__device__ __forceinline__ float fexp2(float x) {
#if __has_builtin(__builtin_amdgcn_exp2f)
    return __builtin_amdgcn_exp2f(x);
#else
    float r; asm volatile("v_exp_f32 %0, %1" : "=v"(r) : "v"(x)); return r;
#endif
}
// raw v_rcp_f32 (~1 ulp): fine for softmax denominator.
__device__ __forceinline__ float frcp(float x) {
#if __has_builtin(__builtin_amdgcn_rcpf)
    return __builtin_amdgcn_rcpf(x);
#else
    float r; asm volatile("v_rcp_f32 %0, %1" : "=v"(r) : "v"(x)); return r;
#endif
}

// swap a.hi32lanes <-> b.lo32lanes (gfx950 v_permlane32_swap_b32)
__device__ __forceinline__ void swap32(unsigned &a, unsigned &b) {
#if __has_builtin(__builtin_amdgcn_permlane32_swap)
    u32x2 r = __builtin_amdgcn_permlane32_swap(a, b, false, false);
    a = r[0]; b = r[1];
#else
    unsigned pa = (unsigned)__shfl_xor((int)a, 32);
    unsigned pb = (unsigned)__shfl_xor((int)b, 32);
    bool hi = (threadIdx.x & 32) != 0;
    unsigned na = hi ? pb : a;
    unsigned nb = hi ? b : pa;
    a = na; b = nb;
#endif
}

__device__ __forceinline__ bf16x8 mk8(unsigned a, unsigned b, unsigned c, unsigned e) {
    union { int4 i; bf16x8 v; } u;
    u.i = make_int4((int)a, (int)b, (int)c, (int)e);
    return u.v;
}

#define GLD_LDS16(gp, lp) __builtin_amdgcn_global_load_lds( \
    (const __attribute__((address_space(1))) unsigned int*)(gp), \
    (__attribute__((address_space(3))) unsigned int*)(lp), 16, 0, 0)

// ---------------- weight transposes (both matrices, one launch) ----------------
__global__ __launch_bounds__(256) void wt_kernel(const float* __restrict__ wqkv,
        const float* __restrict__ wout, unsigned short* __restrict__ WqT,
        unsigned short* __restrict__ WoT) {
    __shared__ float tile[32][33];
    int bx = blockIdx.x;
    const float* in; unsigned short* out; int Cc, c0;
    if (bx < 48) { in = wqkv; out = WqT; Cc = 1536; c0 = bx * 32; }
    else         { in = wout; out = WoT; Cc = 512;  c0 = (bx - 48) * 32; }
    int r0 = blockIdx.y * 32;
    int tx = threadIdx.x & 31, ty = threadIdx.x >> 5;
    #pragma unroll
    for (int i = 0; i < 4; i++) {
        int r = ty + i * 8;
        tile[r][tx] = in[(size_t)(r0 + r) * Cc + c0 + tx];
    }
    __syncthreads();
    #pragma unroll
    for (int i = 0; i < 4; i++) {
        int cr = ty + i * 8;
        out[(size_t)(c0 + cr) * 512 + r0 + tx] = (unsigned short)f2bf_rn(tile[tx][cr]);
    }
}

// ---------------- GroupNorm -> hnT bf16 [n][s][c] ----------------
// Single-pass: the 64 KB group-slab persists in LDS (grid = 2 blocks/CU, so
// 68 KB/block costs no occupancy); normalize pass reads LDS, not global.
__global__ __launch_bounds__(256) void gn_kernel(const float* __restrict__ x,
        const float* __restrict__ scale, const float* __restrict__ bias,
        unsigned short* __restrict__ hnT) {
    int blk = blockIdx.x;                  // n*32+g
    int tid = threadIdx.x;
    int g = blk & 31, n = blk >> 5;
    const float4* src4 = (const float4*)(x + (size_t)blk * 16384);

    __shared__ float xs[16][1028];         // 16 ch x 1024 px, +4 pad
    float s = 0.f, s2 = 0.f;
    #pragma unroll
    for (int k = 0; k < 16; k++) {
        int i = tid + k * 256;
        float4 v = src4[i];
        int c = i >> 8, p4 = (i & 255) * 4;
        *(float4*)&xs[c][p4] = v;
        s  += v.x + v.y + v.z + v.w;
        s2 += v.x*v.x + v.y*v.y + v.z*v.z + v.w*v.w;
    }
    __shared__ float red[256], red2[256];
    red[tid] = s; red2[tid] = s2;
    __syncthreads();
    for (int off = 128; off > 0; off >>= 1) {
        if (tid < off) { red[tid] += red[tid+off]; red2[tid] += red2[tid+off]; }
        __syncthreads();
    }
    __shared__ float sc_s[16], bi_s[16];
    if (tid < 16) {
        float mean = red[0] * (1.f/16384.f);
        float var  = red2[0] * (1.f/16384.f) - mean*mean;
        float rstd = rsqrtf(var + 1e-6f);
        int c = g*16 + tid;
        float sc = scale[c] * rstd;
        sc_s[tid] = sc;
        bi_s[tid] = bias[c] - mean * sc;
    }
    __syncthreads();
    #pragma unroll
    for (int ch = 0; ch < 4; ch++) {
        int sQ = ch*256 + tid;
        unsigned int pk[8];
        #pragma unroll
        for (int c2 = 0; c2 < 8; c2++) {
            float a = xs[c2*2][sQ]   * sc_s[c2*2]   + bi_s[c2*2];
            float b = xs[c2*2+1][sQ] * sc_s[c2*2+1] + bi_s[c2*2+1];
            pk[c2] = pk2bf(a, b);
        }
        unsigned short* op = hnT + ((size_t)(n*1024 + sQ))*512 + g*16;
        *(uint4*)op       = make_uint4(pk[0], pk[1], pk[2], pk[3]);
        *((uint4*)op + 1) = make_uint4(pk[4], pk[5], pk[6], pk[7]);
    }
}

// ---------------- QKV GEMM: D[m][s] = sum_c WqT[m][c]*hnT[s][c] ----------------
// BK=64 per barrier phase (two 32-k sub-tiles): halves barrier-drain count.
__global__ __launch_bounds__(256) void qkv_kernel(
        const unsigned short* __restrict__ WqT, const unsigned short* __restrict__ hnT,
        const float* __restrict__ bqkv,
        unsigned short* __restrict__ qb, unsigned short* __restrict__ kbuf,
        unsigned short* __restrict__ vb) {
    int s0 = blockIdx.x * 128, m0 = blockIdx.y * 128, n = blockIdx.z;
    __shared__ unsigned short At[8192];    // 2 x (128 rows x 32 c), swizzled 16B chunks
    __shared__ unsigned short Bt[8192];
    int tid = threadIdx.x;
    int lane = tid & 63, w = tid >> 6;
    int quad = lane >> 4, tx = lane & 15;
    int moff = (w & 1) * 64, soff = (w >> 1) * 64;

    const unsigned short* Arow = WqT + (size_t)m0 * 512;
    const unsigned short* Brow = hnT + ((size_t)n * 1024 + s0) * 512;

    f32x4v acc[4][4];
    #pragma unroll
    for (int i = 0; i < 4; i++)
        #pragma unroll
        for (int j = 0; j < 4; j++)
            #pragma unroll
            for (int e = 0; e < 4; e++) acc[i][j][e] = 0.f;

    int f1 = tid, f2 = tid + 256;
    int m1 = f1 >> 2, kb1 = ((f1 & 3) - (f1 >> 3)) & 3;
    int m2 = f2 >> 2, kb2 = ((f2 & 3) - (f2 >> 3)) & 3;

    for (int k0 = 0; k0 < 512; k0 += 64) {
        __syncthreads();
        GLD_LDS16(Arow + (size_t)m1*512 + k0 + kb1*8,      At + f1*8);
        GLD_LDS16(Arow + (size_t)m2*512 + k0 + kb2*8,      At + f2*8);
        GLD_LDS16(Arow + (size_t)m1*512 + k0 + 32 + kb1*8, At + 4096 + f1*8);
        GLD_LDS16(Arow + (size_t)m2*512 + k0 + 32 + kb2*8, At + 4096 + f2*8);
        GLD_LDS16(Brow + (size_t)m1*512 + k0 + kb1*8,      Bt + f1*8);
        GLD_LDS16(Brow + (size_t)m2*512 + k0 + kb2*8,      Bt + f2*8);
        GLD_LDS16(Brow + (size_t)m1*512 + k0 + 32 + kb1*8, Bt + 4096 + f1*8);
        GLD_LDS16(Brow + (size_t)m2*512 + k0 + 32 + kb2*8, Bt + 4096 + f2*8);
        __syncthreads();
        #pragma unroll
        for (int kk = 0; kk < 2; kk++) {
            const unsigned short* Ab = At + kk*4096;
            const unsigned short* Bb = Bt + kk*4096;
            bf16x8 af[4], bfr[4];
            #pragma unroll
            for (int mt = 0; mt < 4; mt++) {
                int m = moff + mt*16 + tx;
                int ch = m*4 + ((quad + (m >> 1)) & 3);
                af[mt] = *(const bf16x8*)(Ab + ch*8);
            }
            #pragma unroll
            for (int nt = 0; nt < 4; nt++) {
                int m = soff + nt*16 + tx;
                int ch = m*4 + ((quad + (m >> 1)) & 3);
                bfr[nt] = *(const bf16x8*)(Bb + ch*8);
            }
            #pragma unroll
            for (int mt = 0; mt < 4; mt++)
                #pragma unroll
                for (int nt = 0; nt < 4; nt++)
                    acc[mt][nt] = __builtin_amdgcn_mfma_f32_16x16x32_bf16(
                        af[mt], bfr[nt], acc[mt][nt], 0, 0, 0);
        }
    }

    // Epilogue: q scaled by 0.125*log2(e) (exp2-domain softmax downstream).
    const float QSCL = 0.18033688011112042f;
    #pragma unroll
    for (int mt = 0; mt < 4; mt++) {
        int m = m0 + moff + mt*16 + quad*4;
        int head = m / 192;
        int r = m - head*192;
        int which = r >> 6;
        int d0 = r & 63;
        float4 bia = *(const float4*)(bqkv + m);
        float scl = (which == 0) ? QSCL : 1.0f;
        #pragma unroll
        for (int nt = 0; nt < 4; nt++) {
            int sQ = s0 + soff + nt*16 + tx;
            f32x4v a = acc[mt][nt];
            float v0 = (a[0]+bia.x)*scl, v1 = (a[1]+bia.y)*scl;
            float v2 = (a[2]+bia.z)*scl, v3 = (a[3]+bia.w)*scl;
            if (which < 2) {
                unsigned short* base = (which == 0) ? qb : kbuf;
                unsigned lo = pk2bf(v0, v1), hi2 = pk2bf(v2, v3);
                *(uint2*)(base + (((size_t)(n*8 + head)*1024 + sQ) << 6) + d0) =
                    make_uint2(lo, hi2);
            } else {
                size_t vbase = ((size_t)(n*8 + head)*64 + d0)*1024 + sQ;
                vb[vbase]        = (unsigned short)f2bf_rn(v0);
                vb[vbase + 1024] = (unsigned short)f2bf_rn(v1);
                vb[vbase + 2048] = (unsigned short)f2bf_rn(v2);
                vb[vbase + 3072] = (unsigned short)f2bf_rn(v3);
            }
        }
    }
}

// ---------------- flash attention: 64 q-rows per wave ----------------
// Fixed-max exp2 softmax; S^T = K*Q^T; in-register C->A transform via
// permlane32_swap; denominator on the MFMA pipe (P @ ones).
// Each wave computes TWO 32-q column blocks from ONE pass over the K/V LDS
// fragments -> LDS read traffic per unit work halves (LDS pipe was ~49% of
// runtime). Grid 1024->512 blocks (2 blocks/CU, 74 KB LDS).
// __launch_bounds__(256,2) caps VGPR at 256 (est. ~247 live at peak).
__global__ __launch_bounds__(256, 2) void attn_kernel(
        const unsigned short* __restrict__ qg, const unsigned short* __restrict__ kg,
        const unsigned short* __restrict__ vg, unsigned short* __restrict__ ao) {
    int bid = blockIdx.x;
    int nh = bid & 127, qbk = bid >> 7;     // 4 q-blocks of one head share an XCD
    int tid = threadIdx.x, w = tid >> 6, lane = tid & 63;
    int lq = lane & 31, hi = lane >> 5;
    const unsigned short* Q = qg + (size_t)nh * 65536;
    const unsigned short* K = kg + (size_t)nh * 65536;
    const unsigned short* V = vg + (size_t)nh * 65536;   // [d][t]

    __shared__ unsigned short Klds[2][64*72];            // [t][d], pad 8
    __shared__ unsigned short Vlds[2][64*72];            // [d][t], pad 8

    int q0 = qbk*256 + w*64;
    bf16x8 qfA[4], qfB[4];
    #pragma unroll
    for (int ks = 0; ks < 4; ks++) {
        qfA[ks] = *(const bf16x8*)(Q + ((size_t)(q0 + lq))*64 + ks*16 + hi*8);
        qfB[ks] = *(const bf16x8*)(Q + ((size_t)(q0 + 32 + lq))*64 + ks*16 + hi*8);
    }

    // staging: each thread owns 32B of K-tile and V-tile
    int r = tid >> 2, part = (tid & 3) * 16;
    uint4 ka, kb2, va, vb2;
    ka  = *(const uint4*)(K + (size_t)r*64 + part);
    kb2 = *(const uint4*)(K + (size_t)r*64 + part + 8);
    va  = *(const uint4*)(V + (size_t)r*1024 + part);
    vb2 = *(const uint4*)(V + (size_t)r*1024 + part + 8);

    // all-ones bf16 B operand (layout-irrelevant: every element is 1.0)
    const bf16x8 ONES = mk8(0x3f803f80u, 0x3f803f80u, 0x3f803f80u, 0x3f803f80u);

    f32x16v O0a, O1a, O0b, O1b, Osa, Osb, ZED;
    #pragma unroll
    for (int i = 0; i < 16; i++) {
        O0a[i] = 0.f; O1a[i] = 0.f; O0b[i] = 0.f; O1b[i] = 0.f;
        Osa[i] = 0.f; Osb[i] = 0.f; ZED[i] = 0.f;
    }

    for (int it = 0; it < 16; it++) {
        int buf = it & 1;
        {   // commit staged regs to LDS
            unsigned short* kd = Klds[buf] + r*72 + part;
            *(uint4*)kd = ka; *(uint4*)(kd+8) = kb2;
            unsigned short* vd = Vlds[buf] + r*72 + part;
            *(uint4*)vd = va; *(uint4*)(vd+8) = vb2;
        }
        __syncthreads();
        if (it < 15) {   // prefetch next tile (overlaps compute below)
            int t0 = (it + 1) * 64;
            ka  = *(const uint4*)(K + (size_t)(t0 + r)*64 + part);
            kb2 = *(const uint4*)(K + (size_t)(t0 + r)*64 + part + 8);
            va  = *(const uint4*)(V + (size_t)r*1024 + t0 + part);
            vb2 = *(const uint4*)(V + (size_t)r*1024 + t0 + part + 8);
        }
        const unsigned short* Kb = Klds[buf];
        const unsigned short* Vb = Vlds[buf];

        // joint QK pass: each K-fragment pair feeds 4 MFMAs (2 q-blocks)
        f32x16v S0, S1, U0, U1;
        __builtin_amdgcn_s_setprio(1);
        {
            bf16x8 a0 = *(const bf16x8*)(Kb + lq*72 + hi*8);
            bf16x8 a1 = *(const bf16x8*)(Kb + (32+lq)*72 + hi*8);
            S0 = __builtin_amdgcn_mfma_f32_32x32x16_bf16(a0, qfA[0], ZED, 0, 0, 0);
            S1 = __builtin_amdgcn_mfma_f32_32x32x16_bf16(a1, qfA[0], ZED, 0, 0, 0);
            U0 = __builtin_amdgcn_mfma_f32_32x32x16_bf16(a0, qfB[0], ZED, 0, 0, 0);
            U1 = __builtin_amdgcn_mfma_f32_32x32x16_bf16(a1, qfB[0], ZED, 0, 0, 0);
        }
        #pragma unroll
        for (int ks = 1; ks < 4; ks++) {
            bf16x8 a0 = *(const bf16x8*)(Kb + lq*72 + ks*16 + hi*8);
            bf16x8 a1 = *(const bf16x8*)(Kb + (32+lq)*72 + ks*16 + hi*8);
            S0 = __builtin_amdgcn_mfma_f32_32x32x16_bf16(a0, qfA[ks], S0, 0, 0, 0);
            S1 = __builtin_amdgcn_mfma_f32_32x32x16_bf16(a1, qfA[ks], S1, 0, 0, 0);
            U0 = __builtin_amdgcn_mfma_f32_32x32x16_bf16(a0, qfB[ks], U0, 0, 0, 0);
            U1 = __builtin_amdgcn_mfma_f32_32x32x16_bf16(a1, qfB[ks], U1, 0, 0, 0);
        }
        __builtin_amdgcn_s_setprio(0);

        // softmax block A
        #pragma unroll
        for (int i = 0; i < 16; i++) {
            S0[i] = fexp2(S0[i]);
            S1[i] = fexp2(S1[i]);
        }
        unsigned dA[16];
        #pragma unroll
        for (int p2 = 0; p2 < 8; p2++) {
            dA[p2]     = pk2bf_rne(S0[p2*2], S0[p2*2+1]);
            dA[8 + p2] = pk2bf_rne(S1[p2*2], S1[p2*2+1]);
        }
        swap32(dA[0],  dA[2]);  swap32(dA[1],  dA[3]);
        swap32(dA[4],  dA[6]);  swap32(dA[5],  dA[7]);
        swap32(dA[8],  dA[10]); swap32(dA[9],  dA[11]);
        swap32(dA[12], dA[14]); swap32(dA[13], dA[15]);

        // softmax block B
        #pragma unroll
        for (int i = 0; i < 16; i++) {
            U0[i] = fexp2(U0[i]);
            U1[i] = fexp2(U1[i]);
        }
        unsigned dB[16];
        #pragma unroll
        for (int p2 = 0; p2 < 8; p2++) {
            dB[p2]     = pk2bf_rne(U0[p2*2], U0[p2*2+1]);
            dB[8 + p2] = pk2bf_rne(U1[p2*2], U1[p2*2+1]);
        }
        swap32(dB[0],  dB[2]);  swap32(dB[1],  dB[3]);
        swap32(dB[4],  dB[6]);  swap32(dB[5],  dB[7]);
        swap32(dB[8],  dB[10]); swap32(dB[9],  dB[11]);
        swap32(dB[12], dB[14]); swap32(dB[13], dB[15]);

        // joint PV pass: each V-fragment pair feeds 6 MFMAs (2 q-blocks + sums)
        __builtin_amdgcn_s_setprio(1);
        #pragma unroll
        for (int kc = 0; kc < 4; kc++) {
            bf16x8 paA = mk8(dA[kc*4+0], dA[kc*4+1], dA[kc*4+2], dA[kc*4+3]);
            bf16x8 paB = mk8(dB[kc*4+0], dB[kc*4+1], dB[kc*4+2], dB[kc*4+3]);
            bf16x8 v0 = *(const bf16x8*)(Vb + lq*72 + kc*16 + hi*8);
            bf16x8 v1 = *(const bf16x8*)(Vb + (32+lq)*72 + kc*16 + hi*8);
            O0a = __builtin_amdgcn_mfma_f32_32x32x16_bf16(paA, v0, O0a, 0, 0, 0);
            O1a = __builtin_amdgcn_mfma_f32_32x32x16_bf16(paA, v1, O1a, 0, 0, 0);
            O0b = __builtin_amdgcn_mfma_f32_32x32x16_bf16(paB, v0, O0b, 0, 0, 0);
            O1b = __builtin_amdgcn_mfma_f32_32x32x16_bf16(paB, v1, O1b, 0, 0, 0);
            Osa = __builtin_amdgcn_mfma_f32_32x32x16_bf16(paA, ONES, Osa, 0, 0, 0);
            Osb = __builtin_amdgcn_mfma_f32_32x32x16_bf16(paB, ONES, Osb, 0, 0, 0);
        }
        __builtin_amdgcn_s_setprio(0);
    }

    // Os[reg] = sum_t P[t][q(reg-row)] (all 32 columns identical) -> lane-local
    int n = nh >> 3, h = nh & 7;
    #pragma unroll
    for (int rq = 0; rq < 4; rq++) {
        #pragma unroll
        for (int i = 0; i < 4; i++) {
            int reg = rq*4 + i;
            int sQ = q0 + rq*8 + hi*4 + i;
            float invA = frcp(Osa[reg]);
            float invB = frcp(Osb[reg]);
            size_t rowbA = ((size_t)(n*1024 + sQ))*512 + h*64;
            size_t rowbB = ((size_t)(n*1024 + sQ + 32))*512 + h*64;
            ao[rowbA + lq]      = (unsigned short)f2bf_rn(O0a[reg] * invA);
            ao[rowbA + 32 + lq] = (unsigned short)f2bf_rn(O1a[reg] * invA);
            ao[rowbB + lq]      = (unsigned short)f2bf_rn(O0b[reg] * invB);
            ao[rowbB + 32 + lq] = (unsigned short)f2bf_rn(O1b[reg] * invB);
        }
    }
}

// ---------------- out GEMM: D[s][d] = sum_c aoT[s][c]*WoT[d][c]; +bias+x ----------------
// BK=64 per barrier phase (two 32-k sub-tiles): halves barrier-drain count.
__global__ __launch_bounds__(256) void out_kernel(
        const unsigned short* __restrict__ aoT, const unsigned short* __restrict__ WoT,
        const float* __restrict__ bout, const float* __restrict__ x,
        float* __restrict__ out) {
    int s0 = blockIdx.x * 128, d0b = blockIdx.y * 128, n = blockIdx.z;
    __shared__ unsigned short At[8192];
    __shared__ unsigned short Bt[8192];
    int tid = threadIdx.x;
    int lane = tid & 63, w = tid >> 6;
    int quad = lane >> 4, tx = lane & 15;
    int moff = (w & 1) * 64, noff = (w >> 1) * 64;

    const unsigned short* Arow = aoT + ((size_t)n * 1024 + s0) * 512;
    const unsigned short* Brow = WoT + (size_t)d0b * 512;

    f32x4v acc[4][4];
    #pragma unroll
    for (int i = 0; i < 4; i++)
        #pragma unroll
        for (int j = 0; j < 4; j++)
            #pragma unroll
            for (int e = 0; e < 4; e++) acc[i][j][e] = 0.f;

    int f1 = tid, f2 = tid + 256;
    int m1 = f1 >> 2, kb1 = ((f1 & 3) - (f1 >> 3)) & 3;
    int m2 = f2 >> 2, kb2 = ((f2 & 3) - (f2 >> 3)) & 3;

    for (int k0 = 0; k0 < 512; k0 += 64) {
        __syncthreads();
        GLD_LDS16(Arow + (size_t)m1*512 + k0 + kb1*8,      At + f1*8);
        GLD_LDS16(Arow + (size_t)m2*512 + k0 + kb2*8,      At + f2*8);
        GLD_LDS16(Arow + (size_t)m1*512 + k0 + 32 + kb1*8, At + 4096 + f1*8);
        GLD_LDS16(Arow + (size_t)m2*512 + k0 + 32 + kb2*8, At + 4096 + f2*8);
        GLD_LDS16(Brow + (size_t)m1*512 + k0 + kb1*8,      Bt + f1*8);
        GLD_LDS16(Brow + (size_t)m2*512 + k0 + kb2*8,      Bt + f2*8);
        GLD_LDS16(Brow + (size_t)m1*512 + k0 + 32 + kb1*8, Bt + 4096 + f1*8);
        GLD_LDS16(Brow + (size_t)m2*512 + k0 + 32 + kb2*8, Bt + 4096 + f2*8);
        __syncthreads();
        #pragma unroll
        for (int kk = 0; kk < 2; kk++) {
            const unsigned short* Ab = At + kk*4096;
            const unsigned short* Bb = Bt + kk*4096;
            bf16x8 af[4], bfr[4];
            #pragma unroll
            for (int mt = 0; mt < 4; mt++) {
                int m = moff + mt*16 + tx;
                int ch = m*4 + ((quad + (m >> 1)) & 3);
                af[mt] = *(const bf16x8*)(Ab + ch*8);
            }
            #pragma unroll
            for (int nt = 0; nt < 4; nt++) {
                int m = noff + nt*16 + tx;
                int ch = m*4 + ((quad + (m >> 1)) & 3);
                bfr[nt] = *(const bf16x8*)(Bb + ch*8);
            }
            #pragma unroll
            for (int mt = 0; mt < 4; mt++)
                #pragma unroll
                for (int nt = 0; nt < 4; nt++)
                    acc[mt][nt] = __builtin_amdgcn_mfma_f32_16x16x32_bf16(
                        af[mt], bfr[nt], acc[mt][nt], 0, 0, 0);
        }
    }

    #pragma unroll
    for (int mt = 0; mt < 4; mt++) {
        int sQ = s0 + moff + mt*16 + quad*4;
        #pragma unroll
        for (int nt = 0; nt < 4; nt++) {
            int d = d0b + noff + nt*16 + tx;
            float bo = bout[d];
            size_t base = ((size_t)n*512 + d)*1024 + sQ;
            float4 xv = *(const float4*)(x + base);
            f32x4v a = acc[mt][nt];
            float4 o = make_float4(a[0]+bo+xv.x, a[1]+bo+xv.y, a[2]+bo+xv.z, a[3]+bo+xv.w);
            *(float4*)(out + base) = o;
        }
    }
}

extern "C" void kernel_launch(void* const* d_in, const int* in_sizes, int n_in,
                              void* d_out, int out_size, void* d_ws, size_t ws_size,
                              hipStream_t stream) {
    const float* x    = (const float*)d_in[0];
    const float* gns  = (const float*)d_in[1];
    const float* gnb  = (const float*)d_in[2];
    const float* wqkv = (const float*)d_in[3];
    const float* bqkv = (const float*)d_in[4];
    const float* wout = (const float*)d_in[5];
    const float* bout = (const float*)d_in[6];
    float* out = (float*)d_out;

    char* p = (char*)d_ws;
    size_t off = 0;
    auto carve = [&](size_t bytes) {
        char* r = p + off;
        off = (off + bytes + 255) & ~(size_t)255;
        return r;
    };
    unsigned short* hnT = (unsigned short*)carve((size_t)16*1024*512*2);
    unsigned short* qb2 = (unsigned short*)carve((size_t)128*1024*64*2);
    unsigned short* kb2 = (unsigned short*)carve((size_t)128*1024*64*2);
    unsigned short* vb2 = (unsigned short*)carve((size_t)128*64*1024*2);
    unsigned short* aoT = (unsigned short*)carve((size_t)16*1024*512*2);
    unsigned short* WqT = (unsigned short*)carve((size_t)1536*512*2);
    unsigned short* WoT = (unsigned short*)carve((size_t)512*512*2);

    wt_kernel<<<dim3(64, 16), 256, 0, stream>>>(wqkv, wout, WqT, WoT);
    gn_kernel<<<dim3(512), 256, 0, stream>>>(x, gns, gnb, hnT);
    qkv_kernel<<<dim3(8, 12, 16), 256, 0, stream>>>(WqT, hnT, bqkv, qb2, kb2, vb2);
    attn_kernel<<<dim3(512), 256, 0, stream>>>(qb2, kb2, vb2, aoT);
    out_kernel<<<dim3(8, 4, 16), 256, 0, stream>>>(aoT, WoT, bout, x, out);
}